// Round 11
// baseline (579.942 us; speedup 1.0000x reference)
//
#include <hip/hip_runtime.h>
#include <hip/hip_bf16.h>
#include <math.h>

// Problem constants: N=50000, E=800000, D=64, K=500, C=64
#define DD 64
#define KK 500
#define KPAD 512
#define NPAD 50048   // N padded to multiple of 64
#define NS 50176     // N padded to multiple of 1024 (scan tiles)

typedef __attribute__((ext_vector_type(8))) short bf16x8;
typedef __attribute__((ext_vector_type(4))) float f32x4;

#if defined(__has_builtin)
#if __has_builtin(__builtin_amdgcn_cvt_pk_f32_fp8) && __has_builtin(__builtin_amdgcn_cvt_pk_fp8_f32)
#define HAS_FP8_CVT 1
#endif
#endif

__device__ inline unsigned short f2bf(float f) {
    unsigned u = __float_as_uint(f);
    u += 0x7fffu + ((u >> 16) & 1u);          // RNE
    return (unsigned short)(u >> 16);
}
__device__ inline unsigned packbf(float lo, float hi) {
    return ((unsigned)f2bf(hi) << 16) | (unsigned)f2bf(lo);
}
__device__ inline float bf2f(unsigned short h) {
    return __uint_as_float((unsigned)h << 16);
}

#ifndef HAS_FP8_CVT
__device__ inline float fp8_to_f32_slow(unsigned b) {
    unsigned s = (b >> 7) & 1, e = (b >> 3) & 15, m = b & 7;
    float v = (e == 0) ? ldexpf((float)m, -9) : ldexpf((float)(8 + m), (int)e - 10);
    return s ? -v : v;
}
__device__ inline unsigned f32_to_fp8_slow(float f) {
    unsigned sgn = (__float_as_uint(f) >> 24) & 0x80u;
    float af = fabsf(f);
    if (!(af > 0.f)) return sgn;
    if (af >= 448.f) return sgn | 0x7E;
    int e; frexpf(af, &e);
    int E = e - 1 + 7;
    if (E < 1) { unsigned q = (unsigned)rintf(ldexpf(af, 9)); return sgn | q; }
    unsigned q = (unsigned)rintf(ldexpf(af, 10 - E));
    if (q >= 16) { q = 8; E++; }
    if (E > 15 || (E == 15 && q - 8 >= 7)) return sgn | 0x7E;
    return sgn | ((unsigned)E << 3) | (q - 8);
}
#endif

__device__ inline void accf8(float* a, uint2 v) {
#ifdef HAS_FP8_CVT
    auto f0 = __builtin_amdgcn_cvt_pk_f32_fp8(v.x, false);
    a[0] += f0[0]; a[1] += f0[1];
    auto f1 = __builtin_amdgcn_cvt_pk_f32_fp8(v.x, true);
    a[2] += f1[0]; a[3] += f1[1];
    auto f2 = __builtin_amdgcn_cvt_pk_f32_fp8(v.y, false);
    a[4] += f2[0]; a[5] += f2[1];
    auto f3 = __builtin_amdgcn_cvt_pk_f32_fp8(v.y, true);
    a[6] += f3[0]; a[7] += f3[1];
#else
    a[0] += fp8_to_f32_slow(v.x & 0xff);         a[1] += fp8_to_f32_slow((v.x >> 8) & 0xff);
    a[2] += fp8_to_f32_slow((v.x >> 16) & 0xff); a[3] += fp8_to_f32_slow((v.x >> 24) & 0xff);
    a[4] += fp8_to_f32_slow(v.y & 0xff);         a[5] += fp8_to_f32_slow((v.y >> 8) & 0xff);
    a[6] += fp8_to_f32_slow((v.y >> 16) & 0xff); a[7] += fp8_to_f32_slow((v.y >> 24) & 0xff);
#endif
}

// ---------------- degree histogram ----------------
__global__ void hist_kernel(const int* __restrict__ rowv, const int* __restrict__ colv,
                            int* __restrict__ cnt_row, int* __restrict__ cnt_col, int E) {
    int e = blockIdx.x * blockDim.x + threadIdx.x;
    if (e >= E) return;
    atomicAdd(&cnt_row[rowv[e]], 1);
    atomicAdd(&cnt_col[colv[e]], 1);
}

// ---------------- hierarchical coalesced scan ----------------
__global__ void scanA_kernel(const int* __restrict__ cnt, int* __restrict__ bsum) {
    __shared__ int red[256];
    int t = threadIdx.x;
    int4 c = *(const int4*)&cnt[blockIdx.x * 1024 + t * 4];
    red[t] = c.x + c.y + c.z + c.w;
    __syncthreads();
    for (int o = 128; o > 0; o >>= 1) {
        if (t < o) red[t] += red[t + o];
        __syncthreads();
    }
    if (t == 0) bsum[blockIdx.x] = red[0];
}

__global__ void scanB_kernel(const int* __restrict__ bsum, int* __restrict__ bbase,
                             int* __restrict__ offs_n, int nb) {
    int t = threadIdx.x;
    int v = (t < nb) ? bsum[t] : 0;
    int own = v;
    for (int o = 1; o < 64; o <<= 1) {
        int w = __shfl_up(v, o, 64);
        if (t >= o) v += w;
    }
    if (t < nb) bbase[t] = v - own;
    if (t == 63) *offs_n = v;
}

__global__ void scanC_kernel(const int* __restrict__ cnt, const int* __restrict__ cnt_row,
                             const int* __restrict__ bbase, int* __restrict__ offs,
                             int* __restrict__ cur, float* __restrict__ dinv, int n) {
    __shared__ int sums[256];
    int t = threadIdx.x;
    int i0 = blockIdx.x * 1024 + t * 4;
    int4 c = *(const int4*)&cnt[i0];
    int s = c.x + c.y + c.z + c.w;
    sums[t] = s;
    __syncthreads();
    for (int o = 1; o < 256; o <<= 1) {
        int w = (t >= o) ? sums[t - o] : 0;
        __syncthreads();
        sums[t] += w;
        __syncthreads();
    }
    int base = bbase[blockIdx.x] + sums[t] - s;
    int p0 = base, p1 = base + c.x, p2 = p1 + c.y, p3 = p2 + c.z;
    if (i0 + 0 < n) { offs[i0 + 0] = p0; cur[i0 + 0] = p0; }
    if (i0 + 1 < n) { offs[i0 + 1] = p1; cur[i0 + 1] = p1; }
    if (i0 + 2 < n) { offs[i0 + 2] = p2; cur[i0 + 2] = p2; }
    if (i0 + 3 < n) { offs[i0 + 3] = p3; cur[i0 + 3] = p3; }
    int4 cr = *(const int4*)&cnt_row[i0];
    if (i0 + 0 < n) dinv[i0 + 0] = 1.0f / sqrtf((float)(cr.x + 1));
    if (i0 + 1 < n) dinv[i0 + 1] = 1.0f / sqrtf((float)(cr.y + 1));
    if (i0 + 2 < n) dinv[i0 + 2] = 1.0f / sqrtf((float)(cr.z + 1));
    if (i0 + 3 < n) dinv[i0 + 3] = 1.0f / sqrtf((float)(cr.w + 1));
}

// ---------------- in-CSR placement ----------------
__global__ void place_kernel(const int* __restrict__ rowv, const int* __restrict__ colv,
                             int* __restrict__ cur_col, int* __restrict__ esrc, int E) {
    int e = blockIdx.x * blockDim.x + threadIdx.x;
    if (e >= E) return;
    int p = atomicAdd(&cur_col[colv[e]], 1);
    esrc[p] = rowv[e];
}

// ---------------- xb = bf16(dinv[i] * x[i]) ----------------
__global__ void xscale_kernel(const float* __restrict__ x, const float* __restrict__ dinv,
                              unsigned short* __restrict__ xb, int n16) {
    int idx = blockIdx.x * blockDim.x + threadIdx.x;
    if (idx >= n16) return;
    int i = idx >> 4;
    float di = dinv[i];
    float4 v = ((const float4*)x)[idx];
    uint2 o;
    o.x = packbf(di * v.x, di * v.y);
    o.y = packbf(di * v.z, di * v.w);
    ((uint2*)xb)[idx] = o;
}

// ---------------- weight prep ----------------
__global__ void wprep_kernel(const float* __restrict__ Wa, const float* __restrict__ We,
                             unsigned short* __restrict__ WaT, unsigned short* __restrict__ WeT) {
    int idx = blockIdx.x * blockDim.x + threadIdx.x;
    if (idx < KPAD * 64) {
        int c = idx >> 6, d = idx & 63;
        float v = (c < KK) ? Wa[(size_t)d * KK + c] : 0.f;
        WaT[idx] = f2bf(v);
    } else {
        int j = idx - KPAD * 64;
        int c = j >> 6, d = j & 63;
        WeT[j] = f2bf(We[(size_t)d * 64 + c]);
    }
}

// ---- u[i] = xb[i] + sum_{in} xb[s]; ub = bf16(u);  t[i] = dinv[i] + sum_{in} dinv[s] ----
__global__ void agg_kernel(const unsigned short* __restrict__ xb, const float* __restrict__ dinv,
                           const int* __restrict__ offs, const int* __restrict__ esrc,
                           float* __restrict__ u, float* __restrict__ t,
                           unsigned short* __restrict__ ub, int n) {
    int wv = (blockIdx.x * blockDim.x + threadIdx.x) >> 6;
    int ln = threadIdx.x & 63;
    if (wv >= NPAD) return;
    if (wv >= n) {
        ub[(size_t)wv * 64 + ln] = 0;
        return;
    }
    float di = dinv[wv];
    float acc = bf2f(xb[(size_t)wv * 64 + ln]);
    float ts = 0.f;
    int p = offs[wv], pend = offs[wv + 1];
    for (; p + 7 < pend; p += 8) {
        int s0 = esrc[p],     s1 = esrc[p + 1], s2 = esrc[p + 2], s3 = esrc[p + 3];
        int s4 = esrc[p + 4], s5 = esrc[p + 5], s6 = esrc[p + 6], s7 = esrc[p + 7];
        unsigned short h0 = xb[(size_t)s0 * 64 + ln];
        unsigned short h1 = xb[(size_t)s1 * 64 + ln];
        unsigned short h2 = xb[(size_t)s2 * 64 + ln];
        unsigned short h3 = xb[(size_t)s3 * 64 + ln];
        unsigned short h4 = xb[(size_t)s4 * 64 + ln];
        unsigned short h5 = xb[(size_t)s5 * 64 + ln];
        unsigned short h6 = xb[(size_t)s6 * 64 + ln];
        unsigned short h7 = xb[(size_t)s7 * 64 + ln];
        float w0 = dinv[s0], w1 = dinv[s1], w2 = dinv[s2], w3 = dinv[s3];
        float w4 = dinv[s4], w5 = dinv[s5], w6 = dinv[s6], w7 = dinv[s7];
        acc += bf2f(h0) + bf2f(h1) + bf2f(h2) + bf2f(h3)
             + bf2f(h4) + bf2f(h5) + bf2f(h6) + bf2f(h7);
        ts += w0 + w1 + w2 + w3 + w4 + w5 + w6 + w7;
    }
    for (; p < pend; ++p) {
        int s = esrc[p];
        acc += bf2f(xb[(size_t)s * 64 + ln]);
        ts += dinv[s];
    }
    u[(size_t)wv * 64 + ln] = acc;
    ub[(size_t)wv * 64 + ln] = f2bf(acc);
    if (ln == 0) t[wv] = di + ts;
}

// ---- fused v3 (MFMA): L^T = WaT @ ub^T (softmax -> S_T bf16 + Sf8 e4m3)
//      and Z^T = WeT @ ub^T -> Z_T bf16 directly. Block = 64 nodes (4 waves x 16). ----
#define F8ROW 520
__global__ void __launch_bounds__(256) fused_s2_kernel(
        const unsigned short* __restrict__ ub, const unsigned short* __restrict__ WaT,
        const unsigned short* __restrict__ WeT,
        const float* __restrict__ ba, const float* __restrict__ be,
        const float* __restrict__ dinv, const float* __restrict__ tsum,
        unsigned short* __restrict__ S_T, unsigned char* __restrict__ Sf8,
        unsigned short* __restrict__ Z_T, int n) {
    __shared__ float bs[512];
    __shared__ float bes[64];
    __shared__ unsigned char f8[64 * F8ROW];
    int t = threadIdx.x;
    int n0 = blockIdx.x * 64;
    {
        float b0 = (t * 2     < KK) ? ba[t * 2]     : 0.f;
        float b1 = (t * 2 + 1 < KK) ? ba[t * 2 + 1] : 0.f;
        bs[t * 2] = b0; bs[t * 2 + 1] = b1;
        if (t < 64) bes[t] = be[t];
    }
    __syncthreads();
    int wv = t >> 6, ln = t & 63;
    int nl = ln & 15;
    int g  = ln >> 4;
    int node = n0 + wv * 16 + nl;
    float sd = (node < n) ? dinv[node] : 0.f;
    float st = (node < n) ? tsum[node] : 0.f;
    const unsigned short* brow = ub + (size_t)node * 64;
    bf16x8 bf0 = *(const bf16x8*)&brow[g * 8];
    bf16x8 bf1 = *(const bf16x8*)&brow[32 + g * 8];
    f32x4 acc[32];
#pragma unroll
    for (int mt = 0; mt < 32; ++mt) {
        const unsigned short* arow = WaT + (size_t)(mt * 16 + nl) * 64;
        bf16x8 af0 = *(const bf16x8*)&arow[g * 8];
        bf16x8 af1 = *(const bf16x8*)&arow[32 + g * 8];
        f32x4 a = __builtin_amdgcn_mfma_f32_16x16x32_bf16(af0, bf0, (f32x4){0.f,0.f,0.f,0.f}, 0, 0, 0);
        acc[mt] = __builtin_amdgcn_mfma_f32_16x16x32_bf16(af1, bf1, a, 0, 0, 0);
    }
    float m = -1e30f;
#pragma unroll
    for (int mt = 0; mt < 32; ++mt) {
#pragma unroll
        for (int r = 0; r < 4; ++r) {
            int cl = mt * 16 + g * 4 + r;
            float L = sd * (acc[mt][r] + st * bs[cl]);
            if (cl >= KK) L = -1e30f;
            acc[mt][r] = L;
            m = fmaxf(m, L);
        }
    }
    m = fmaxf(m, __shfl_xor(m, 16, 64));
    m = fmaxf(m, __shfl_xor(m, 32, 64));
    float ssum = 0.f;
#pragma unroll
    for (int mt = 0; mt < 32; ++mt) {
#pragma unroll
        for (int r = 0; r < 4; ++r) {
            float e = expf(acc[mt][r] - m);
            acc[mt][r] = e;
            ssum += e;
        }
    }
    ssum += __shfl_xor(ssum, 16, 64);
    ssum += __shfl_xor(ssum, 32, 64);
    float rs = (node < n) ? (1.0f / ssum) : 0.f;
    float sc = 256.f * rs;
    unsigned char* frow = &f8[(wv * 16 + nl) * F8ROW];
#pragma unroll
    for (int mt = 0; mt < 32; ++mt) {
#pragma unroll
        for (int r = 0; r < 4; ++r) {
            int cl = mt * 16 + g * 4 + r;
            S_T[(size_t)cl * NPAD + node] = f2bf(acc[mt][r] * rs);
        }
#ifdef HAS_FP8_CVT
        int pk = __builtin_amdgcn_cvt_pk_fp8_f32(acc[mt][0] * sc, acc[mt][1] * sc, 0, false);
        pk     = __builtin_amdgcn_cvt_pk_fp8_f32(acc[mt][2] * sc, acc[mt][3] * sc, pk, true);
#else
        int pk = (int)(f32_to_fp8_slow(acc[mt][0]*sc) | (f32_to_fp8_slow(acc[mt][1]*sc) << 8) |
                       (f32_to_fp8_slow(acc[mt][2]*sc) << 16) | (f32_to_fp8_slow(acc[mt][3]*sc) << 24));
#endif
        *(unsigned*)&frow[mt * 16 + g * 4] = (unsigned)pk;
    }
#pragma unroll
    for (int mt = 0; mt < 4; ++mt) {
        const unsigned short* arow = WeT + (size_t)(mt * 16 + nl) * 64;
        bf16x8 af0 = *(const bf16x8*)&arow[g * 8];
        bf16x8 af1 = *(const bf16x8*)&arow[32 + g * 8];
        f32x4 a = __builtin_amdgcn_mfma_f32_16x16x32_bf16(af0, bf0, (f32x4){0.f,0.f,0.f,0.f}, 0, 0, 0);
        a = __builtin_amdgcn_mfma_f32_16x16x32_bf16(af1, bf1, a, 0, 0, 0);
#pragma unroll
        for (int r = 0; r < 4; ++r) {
            int ch = mt * 16 + g * 4 + r;
            float z = sd * (a[r] + st * bes[ch]);
            Z_T[(size_t)ch * NPAD + node] = f2bf(z);
        }
    }
    __syncthreads();
#pragma unroll
    for (int h = 0; h < 8; ++h) {
        int idx = t + h * 256;
        int row = idx >> 5;
        int off = (idx & 31) * 16;
        uint4 vv = *(const uint4*)&f8[row * F8ROW + off];
        int grow = n0 + row;
        if (grow < n) *(uint4*)&Sf8[(size_t)grow * KPAD + off] = vv;
    }
}

// -------- G = A^T S via in-CSR over fp8 S, TRANSPOSED bf16 out. 512 threads (8 waves). --------
#define GT_ROWS 32
__global__ void __launch_bounds__(512) g_agg_t_kernel(
        const unsigned char* __restrict__ Sf8, const int* __restrict__ offs,
        const int* __restrict__ esrc, unsigned short* __restrict__ G_T, int n) {
    __shared__ unsigned short tl[GT_ROWS * 520];
    int base = blockIdx.x * GT_ROWS;
    int wv = threadIdx.x >> 6, ln = threadIdx.x & 63;   // 8 waves
    const uint2* S2 = (const uint2*)Sf8;
#pragma unroll
    for (int i = 0; i < GT_ROWS / 8; ++i) {             // 4 nodes per wave
        int r = wv * (GT_ROWS / 8) + i;
        int node = base + r;
        float a[8] = {0.f,0.f,0.f,0.f,0.f,0.f,0.f,0.f};
        if (node < n) {
            int p = offs[node], pend = offs[node + 1];
            for (; p + 7 < pend; p += 8) {
                int s0 = esrc[p],     s1 = esrc[p + 1], s2 = esrc[p + 2], s3 = esrc[p + 3];
                int s4 = esrc[p + 4], s5 = esrc[p + 5], s6 = esrc[p + 6], s7 = esrc[p + 7];
                uint2 v0 = S2[(size_t)s0 * 64 + ln];
                uint2 v1 = S2[(size_t)s1 * 64 + ln];
                uint2 v2 = S2[(size_t)s2 * 64 + ln];
                uint2 v3 = S2[(size_t)s3 * 64 + ln];
                uint2 v4 = S2[(size_t)s4 * 64 + ln];
                uint2 v5 = S2[(size_t)s5 * 64 + ln];
                uint2 v6 = S2[(size_t)s6 * 64 + ln];
                uint2 v7 = S2[(size_t)s7 * 64 + ln];
                accf8(a, v0); accf8(a, v1); accf8(a, v2); accf8(a, v3);
                accf8(a, v4); accf8(a, v5); accf8(a, v6); accf8(a, v7);
            }
            for (; p < pend; ++p) {
                uint2 v = S2[(size_t)esrc[p] * 64 + ln];
                accf8(a, v);
            }
        }
        const float inv = 1.0f / 256.f;
        uint4 o;
        o.x = packbf(a[0] * inv, a[1] * inv); o.y = packbf(a[2] * inv, a[3] * inv);
        o.z = packbf(a[4] * inv, a[5] * inv); o.w = packbf(a[6] * inv, a[7] * inv);
        *(uint4*)&tl[r * 520 + ln * 8] = o;
    }
    __syncthreads();
    {
        int k = threadIdx.x;              // 0..511
        unsigned wb[8];
#pragma unroll
        for (int j = 0; j < 8; ++j) {
            unsigned short lo = tl[(2 * j)     * 520 + k];
            unsigned short hi = tl[(2 * j + 1) * 520 + k];
            wb[j] = ((unsigned)hi << 16) | (unsigned)lo;
        }
        unsigned wc[8];
#pragma unroll
        for (int j = 0; j < 8; ++j) {
            unsigned short lo = tl[(16 + 2 * j) * 520 + k];
            unsigned short hi = tl[(17 + 2 * j) * 520 + k];
            wc[j] = ((unsigned)hi << 16) | (unsigned)lo;
        }
        size_t ob = (size_t)k * NPAD + base;
        *(uint4*)&G_T[ob]      = make_uint4(wb[0], wb[1], wb[2], wb[3]);
        *(uint4*)&G_T[ob + 8]  = make_uint4(wb[4], wb[5], wb[6], wb[7]);
        *(uint4*)&G_T[ob + 16] = make_uint4(wc[0], wc[1], wc[2], wc[3]);
        *(uint4*)&G_T[ob + 24] = make_uint4(wc[4], wc[5], wc[6], wc[7]);
    }
}

// ---------------- MFMA TN GEMM 128x128, atomic epilogue (next_X) ----------------
__global__ void __launch_bounds__(256) mfma_tn_kernel(
        const unsigned short* __restrict__ A_T, const unsigned short* __restrict__ B_T,
        float* __restrict__ out, int nPer, int KA, int KB) {
    const int a0 = blockIdx.x * 128, b0 = blockIdx.y * 128;
    const int nbeg = blockIdx.z * nPer;
    const int nend = min(nbeg + nPer, NPAD);
    __shared__ unsigned short Al[128 * 72];
    __shared__ unsigned short Bl[128 * 72];
    const int t = threadIdx.x;
    const int ln = t & 63, wv = t >> 6;
    const int wa = (wv & 1) * 64, wb = (wv >> 1) * 64;
    const int lm = ln & 15, lk = (ln >> 4) * 8;
    const bool active = (b0 + wb) < KB;       // waves over poison B cols skip compute
    f32x4 acc[4][4];
#pragma unroll
    for (int i = 0; i < 4; ++i)
#pragma unroll
        for (int j = 0; j < 4; ++j) acc[i][j] = (f32x4){0.f, 0.f, 0.f, 0.f};
    for (int nb = nbeg; nb < nend; nb += 64) {
        __syncthreads();
#pragma unroll
        for (int i = 0; i < 4; ++i) {
            int idx = t + i * 256;
            int r = idx >> 3, c8 = (idx & 7) * 8;
            uint4 va = *(const uint4*)&A_T[(size_t)(a0 + r) * NPAD + nb + c8];
            uint4 vb = *(const uint4*)&B_T[(size_t)(b0 + r) * NPAD + nb + c8];
            *(uint4*)&Al[r * 72 + c8] = va;
            *(uint4*)&Bl[r * 72 + c8] = vb;
        }
        __syncthreads();
        if (!active) continue;
#pragma unroll
        for (int ks = 0; ks < 64; ks += 32) {
            bf16x8 af[4], bfr[4];
#pragma unroll
            for (int i = 0; i < 4; ++i)
                af[i] = *(const bf16x8*)&Al[(wa + i * 16 + lm) * 72 + ks + lk];
#pragma unroll
            for (int j = 0; j < 4; ++j)
                bfr[j] = *(const bf16x8*)&Bl[(wb + j * 16 + lm) * 72 + ks + lk];
#pragma unroll
            for (int i = 0; i < 4; ++i)
#pragma unroll
                for (int j = 0; j < 4; ++j)
                    acc[i][j] = __builtin_amdgcn_mfma_f32_16x16x32_bf16(af[i], bfr[j], acc[i][j], 0, 0, 0);
        }
    }
    if (!active) return;
#pragma unroll
    for (int i = 0; i < 4; ++i) {
#pragma unroll
        for (int j = 0; j < 4; ++j) {
            int bg = b0 + wb + j * 16 + lm;
            if (bg >= KB) continue;
#pragma unroll
            for (int r = 0; r < 4; ++r) {
                int ag = a0 + wa + i * 16 + (ln >> 4) * 4 + r;
                if (ag < KA) atomicAdd(&out[(size_t)ag * KB + bg], acc[i][j][r]);
            }
        }
    }
}

// ---------------- MFMA TN GEMM 256a x 128b, atomic epilogue (next_A) ----------------
__global__ void __launch_bounds__(256) mfma_tn256_kernel(
        const unsigned short* __restrict__ A_T, const unsigned short* __restrict__ B_T,
        float* __restrict__ out, int nPer, int KA, int KB) {
    const int a0 = blockIdx.x * 256, b0 = blockIdx.y * 128;
    const int nbeg = blockIdx.z * nPer;
    const int nend = min(nbeg + nPer, NPAD);
    __shared__ unsigned short Al[256 * 72];
    __shared__ unsigned short Bl[128 * 72];
    const int t = threadIdx.x;
    const int ln = t & 63, wv = t >> 6;
    const int wa = wv * 64;
    const int lm = ln & 15, lk = (ln >> 4) * 8;
    f32x4 acc[4][8];
#pragma unroll
    for (int i = 0; i < 4; ++i)
#pragma unroll
        for (int j = 0; j < 8; ++j) acc[i][j] = (f32x4){0.f, 0.f, 0.f, 0.f};
    for (int nb = nbeg; nb < nend; nb += 64) {
        __syncthreads();
#pragma unroll
        for (int i = 0; i < 8; ++i) {
            int idx = t + i * 256;
            int r = idx >> 3, c8 = (idx & 7) * 8;
            uint4 va = *(const uint4*)&A_T[(size_t)(a0 + r) * NPAD + nb + c8];
            *(uint4*)&Al[r * 72 + c8] = va;
        }
#pragma unroll
        for (int i = 0; i < 4; ++i) {
            int idx = t + i * 256;
            int r = idx >> 3, c8 = (idx & 7) * 8;
            uint4 vb = *(const uint4*)&B_T[(size_t)(b0 + r) * NPAD + nb + c8];
            *(uint4*)&Bl[r * 72 + c8] = vb;
        }
        __syncthreads();
#pragma unroll
        for (int ks = 0; ks < 64; ks += 32) {
            bf16x8 af[4], bfr[8];
#pragma unroll
            for (int i = 0; i < 4; ++i)
                af[i] = *(const bf16x8*)&Al[(wa + i * 16 + lm) * 72 + ks + lk];
#pragma unroll
            for (int j = 0; j < 8; ++j)
                bfr[j] = *(const bf16x8*)&Bl[(j * 16 + lm) * 72 + ks + lk];
#pragma unroll
            for (int i = 0; i < 4; ++i)
#pragma unroll
                for (int j = 0; j < 8; ++j)
                    acc[i][j] = __builtin_amdgcn_mfma_f32_16x16x32_bf16(af[i], bfr[j], acc[i][j], 0, 0, 0);
        }
    }
#pragma unroll
    for (int i = 0; i < 4; ++i) {
#pragma unroll
        for (int j = 0; j < 8; ++j) {
            int bg = b0 + j * 16 + lm;
            if (bg >= KB) continue;
#pragma unroll
            for (int r = 0; r < 4; ++r) {
                int ag = a0 + wa + i * 16 + (ln >> 4) * 4 + r;
                if (ag < KA) atomicAdd(&out[(size_t)ag * KB + bg], acc[i][j][r]);
            }
        }
    }
}

extern "C" void kernel_launch(void* const* d_in, const int* in_sizes, int n_in,
                              void* d_out, int out_size, void* d_ws, size_t ws_size,
                              hipStream_t stream) {
    const float* x        = (const float*)d_in[0];
    const int*   ei       = (const int*)d_in[1];
    const float* W_embed  = (const float*)d_in[2];
    const float* b_embed  = (const float*)d_in[3];
    const float* W_assign = (const float*)d_in[4];
    const float* b_assign = (const float*)d_in[5];

    const int N = in_sizes[0] / DD;     // 50000
    const int E = in_sizes[1] / 2;      // 800000
    const int C = in_sizes[3];          // 64
    const int K = in_sizes[5];          // 500

    const int* rowv = ei;
    const int* colv = ei + E;

    char* p = (char*)d_ws;
    auto alloc = [&](size_t bytes) -> void* {
        void* r = (void*)p;
        p += (bytes + 255) & ~(size_t)255;
        return r;
    };
    int*   cnt      = (int*)alloc((size_t)2 * NS * 4);
    int*   cnt_col  = cnt;
    int*   cnt_row  = cnt + NS;
    int*   offs_col = (int*)alloc((size_t)(N + 1) * 4);
    int*   cur_col  = (int*)alloc((size_t)N * 4);
    int*   bsum     = (int*)alloc(64 * 4);
    int*   bbase    = (int*)alloc(64 * 4);
    float* dinv     = (float*)alloc((size_t)N * 4);
    float* tsum     = (float*)alloc((size_t)N * 4);
    int*   esrc     = (int*)alloc((size_t)E * 4);
    float* u        = (float*)alloc((size_t)N * DD * 4);
    unsigned short* xb   = (unsigned short*)alloc((size_t)N * DD * 2);
    unsigned short* ubuf = (unsigned short*)alloc((size_t)NPAD * DD * 2);
    unsigned short* WaT  = (unsigned short*)alloc((size_t)KPAD * DD * 2);
    unsigned short* WeT  = (unsigned short*)alloc((size_t)DD * DD * 2);
    unsigned char*  Sf8  = (unsigned char*)alloc((size_t)N * KPAD);
    unsigned short* S_T  = (unsigned short*)alloc((size_t)KPAD * NPAD * 2);
    unsigned short* G_T  = (unsigned short*)alloc((size_t)KPAD * NPAD * 2);
    unsigned short* Z_T  = (unsigned short*)alloc((size_t)128 * NPAD * 2);

    const int nPer = 1088, ZSK = 46;    // 1088*46 == NPAD

    float* outX = (float*)d_out;            // [500][64]
    float* outA = outX + (size_t)K * C;     // [500][500]

    const int NB = (N + 1023) / 1024;

    (void)hipMemsetAsync(cnt, 0, (size_t)2 * NS * 4, stream);
    (void)hipMemsetAsync(d_out, 0, (size_t)out_size * 4, stream);

    hist_kernel<<<(E + 255) / 256, 256, 0, stream>>>(rowv, colv, cnt_row, cnt_col, E);
    scanA_kernel<<<NB, 256, 0, stream>>>(cnt_col, bsum);
    scanB_kernel<<<1, 64, 0, stream>>>(bsum, bbase, &offs_col[N], NB);
    scanC_kernel<<<NB, 256, 0, stream>>>(cnt_col, cnt_row, bbase, offs_col, cur_col, dinv, N);
    place_kernel<<<(E + 255) / 256, 256, 0, stream>>>(rowv, colv, cur_col, esrc, E);

    xscale_kernel<<<(N * 16 + 255) / 256, 256, 0, stream>>>(x, dinv, xb, N * 16);
    wprep_kernel<<<((KPAD + DD) * DD) / 256, 256, 0, stream>>>(W_assign, W_embed, WaT, WeT);

    agg_kernel<<<NPAD / 4, 256, 0, stream>>>(xb, dinv, offs_col, esrc, u, tsum, ubuf, N);

    fused_s2_kernel<<<NPAD / 64, 256, 0, stream>>>(ubuf, WaT, WeT, b_assign, b_embed,
                                                   dinv, tsum, S_T, Sf8, Z_T, N);

    g_agg_t_kernel<<<NPAD / GT_ROWS, 512, 0, stream>>>(Sf8, offs_col, esrc, G_T, N);

    // next_X = S^T @ Z : atomic split-K into outX
    {
        dim3 g(4, 1, ZSK);
        mfma_tn_kernel<<<g, 256, 0, stream>>>(S_T, Z_T, outX, nPer, K, C);
    }
    // next_A = G^T @ S : atomic split-K into outA
    {
        dim3 g(2, 4, ZSK);
        mfma_tn256_kernel<<<g, 256, 0, stream>>>(G_T, S_T, outA, nPer, K, K);
    }
}

// Round 12
// 532.275 us; speedup vs baseline: 1.0896x; 1.0896x over previous
//
#include <hip/hip_runtime.h>
#include <hip/hip_bf16.h>
#include <math.h>

// Problem constants: N=50000, E=800000, D=64, K=500, C=64
#define DD 64
#define KK 500
#define KPAD 512
#define NPAD 50048   // N padded to multiple of 64
#define NS 50176     // N padded to multiple of 1024 (scan tiles)

typedef __attribute__((ext_vector_type(8))) short bf16x8;
typedef __attribute__((ext_vector_type(4))) float f32x4;

#if defined(__has_builtin)
#if __has_builtin(__builtin_amdgcn_cvt_pk_f32_fp8) && __has_builtin(__builtin_amdgcn_cvt_pk_fp8_f32)
#define HAS_FP8_CVT 1
#endif
#endif

__device__ inline unsigned short f2bf(float f) {
    unsigned u = __float_as_uint(f);
    u += 0x7fffu + ((u >> 16) & 1u);          // RNE
    return (unsigned short)(u >> 16);
}
__device__ inline unsigned packbf(float lo, float hi) {
    return ((unsigned)f2bf(hi) << 16) | (unsigned)f2bf(lo);
}
__device__ inline float bf2f(unsigned short h) {
    return __uint_as_float((unsigned)h << 16);
}

#ifndef HAS_FP8_CVT
__device__ inline float fp8_to_f32_slow(unsigned b) {
    unsigned s = (b >> 7) & 1, e = (b >> 3) & 15, m = b & 7;
    float v = (e == 0) ? ldexpf((float)m, -9) : ldexpf((float)(8 + m), (int)e - 10);
    return s ? -v : v;
}
__device__ inline unsigned f32_to_fp8_slow(float f) {
    unsigned sgn = (__float_as_uint(f) >> 24) & 0x80u;
    float af = fabsf(f);
    if (!(af > 0.f)) return sgn;
    if (af >= 448.f) return sgn | 0x7E;
    int e; frexpf(af, &e);
    int E = e - 1 + 7;
    if (E < 1) { unsigned q = (unsigned)rintf(ldexpf(af, 9)); return sgn | q; }
    unsigned q = (unsigned)rintf(ldexpf(af, 10 - E));
    if (q >= 16) { q = 8; E++; }
    if (E > 15 || (E == 15 && q - 8 >= 7)) return sgn | 0x7E;
    return sgn | ((unsigned)E << 3) | (q - 8);
}
#endif

__device__ inline void accf8(float* a, uint2 v) {
#ifdef HAS_FP8_CVT
    auto f0 = __builtin_amdgcn_cvt_pk_f32_fp8(v.x, false);
    a[0] += f0[0]; a[1] += f0[1];
    auto f1 = __builtin_amdgcn_cvt_pk_f32_fp8(v.x, true);
    a[2] += f1[0]; a[3] += f1[1];
    auto f2 = __builtin_amdgcn_cvt_pk_f32_fp8(v.y, false);
    a[4] += f2[0]; a[5] += f2[1];
    auto f3 = __builtin_amdgcn_cvt_pk_f32_fp8(v.y, true);
    a[6] += f3[0]; a[7] += f3[1];
#else
    a[0] += fp8_to_f32_slow(v.x & 0xff);         a[1] += fp8_to_f32_slow((v.x >> 8) & 0xff);
    a[2] += fp8_to_f32_slow((v.x >> 16) & 0xff); a[3] += fp8_to_f32_slow((v.x >> 24) & 0xff);
    a[4] += fp8_to_f32_slow(v.y & 0xff);         a[5] += fp8_to_f32_slow((v.y >> 8) & 0xff);
    a[6] += fp8_to_f32_slow((v.y >> 16) & 0xff); a[7] += fp8_to_f32_slow((v.y >> 24) & 0xff);
#endif
}

// ---------------- degree histogram ----------------
__global__ void hist_kernel(const int* __restrict__ rowv, const int* __restrict__ colv,
                            int* __restrict__ cnt_row, int* __restrict__ cnt_col, int E) {
    int e = blockIdx.x * blockDim.x + threadIdx.x;
    if (e >= E) return;
    atomicAdd(&cnt_row[rowv[e]], 1);
    atomicAdd(&cnt_col[colv[e]], 1);
}

// ---------------- hierarchical coalesced scan ----------------
__global__ void scanA_kernel(const int* __restrict__ cnt, int* __restrict__ bsum) {
    __shared__ int red[256];
    int t = threadIdx.x;
    int4 c = *(const int4*)&cnt[blockIdx.x * 1024 + t * 4];
    red[t] = c.x + c.y + c.z + c.w;
    __syncthreads();
    for (int o = 128; o > 0; o >>= 1) {
        if (t < o) red[t] += red[t + o];
        __syncthreads();
    }
    if (t == 0) bsum[blockIdx.x] = red[0];
}

__global__ void scanB_kernel(const int* __restrict__ bsum, int* __restrict__ bbase,
                             int* __restrict__ offs_n, int nb) {
    int t = threadIdx.x;
    int v = (t < nb) ? bsum[t] : 0;
    int own = v;
    for (int o = 1; o < 64; o <<= 1) {
        int w = __shfl_up(v, o, 64);
        if (t >= o) v += w;
    }
    if (t < nb) bbase[t] = v - own;
    if (t == 63) *offs_n = v;
}

__global__ void scanC_kernel(const int* __restrict__ cnt, const int* __restrict__ cnt_row,
                             const int* __restrict__ bbase, int* __restrict__ offs,
                             int* __restrict__ cur, float* __restrict__ dinv, int n) {
    __shared__ int sums[256];
    int t = threadIdx.x;
    int i0 = blockIdx.x * 1024 + t * 4;
    int4 c = *(const int4*)&cnt[i0];
    int s = c.x + c.y + c.z + c.w;
    sums[t] = s;
    __syncthreads();
    for (int o = 1; o < 256; o <<= 1) {
        int w = (t >= o) ? sums[t - o] : 0;
        __syncthreads();
        sums[t] += w;
        __syncthreads();
    }
    int base = bbase[blockIdx.x] + sums[t] - s;
    int p0 = base, p1 = base + c.x, p2 = p1 + c.y, p3 = p2 + c.z;
    if (i0 + 0 < n) { offs[i0 + 0] = p0; cur[i0 + 0] = p0; }
    if (i0 + 1 < n) { offs[i0 + 1] = p1; cur[i0 + 1] = p1; }
    if (i0 + 2 < n) { offs[i0 + 2] = p2; cur[i0 + 2] = p2; }
    if (i0 + 3 < n) { offs[i0 + 3] = p3; cur[i0 + 3] = p3; }
    int4 cr = *(const int4*)&cnt_row[i0];
    if (i0 + 0 < n) dinv[i0 + 0] = 1.0f / sqrtf((float)(cr.x + 1));
    if (i0 + 1 < n) dinv[i0 + 1] = 1.0f / sqrtf((float)(cr.y + 1));
    if (i0 + 2 < n) dinv[i0 + 2] = 1.0f / sqrtf((float)(cr.z + 1));
    if (i0 + 3 < n) dinv[i0 + 3] = 1.0f / sqrtf((float)(cr.w + 1));
}

// ---------------- in-CSR placement ----------------
__global__ void place_kernel(const int* __restrict__ rowv, const int* __restrict__ colv,
                             int* __restrict__ cur_col, int* __restrict__ esrc, int E) {
    int e = blockIdx.x * blockDim.x + threadIdx.x;
    if (e >= E) return;
    int p = atomicAdd(&cur_col[colv[e]], 1);
    esrc[p] = rowv[e];
}

// ---------------- xb = bf16(dinv[i] * x[i]) ----------------
__global__ void xscale_kernel(const float* __restrict__ x, const float* __restrict__ dinv,
                              unsigned short* __restrict__ xb, int n16) {
    int idx = blockIdx.x * blockDim.x + threadIdx.x;
    if (idx >= n16) return;
    int i = idx >> 4;
    float di = dinv[i];
    float4 v = ((const float4*)x)[idx];
    uint2 o;
    o.x = packbf(di * v.x, di * v.y);
    o.y = packbf(di * v.z, di * v.w);
    ((uint2*)xb)[idx] = o;
}

// ---------------- weight prep ----------------
__global__ void wprep_kernel(const float* __restrict__ Wa, const float* __restrict__ We,
                             unsigned short* __restrict__ WaT, unsigned short* __restrict__ WeT) {
    int idx = blockIdx.x * blockDim.x + threadIdx.x;
    if (idx < KPAD * 64) {
        int c = idx >> 6, d = idx & 63;
        float v = (c < KK) ? Wa[(size_t)d * KK + c] : 0.f;
        WaT[idx] = f2bf(v);
    } else {
        int j = idx - KPAD * 64;
        int c = j >> 6, d = j & 63;
        WeT[j] = f2bf(We[(size_t)d * 64 + c]);
    }
}

// ---- u[i] = xb[i] + sum_{in} xb[s]; ub = bf16(u);  t[i] = dinv[i] + sum_{in} dinv[s] ----
__global__ void agg_kernel(const unsigned short* __restrict__ xb, const float* __restrict__ dinv,
                           const int* __restrict__ offs, const int* __restrict__ esrc,
                           float* __restrict__ u, float* __restrict__ t,
                           unsigned short* __restrict__ ub, int n) {
    int wv = (blockIdx.x * blockDim.x + threadIdx.x) >> 6;
    int ln = threadIdx.x & 63;
    if (wv >= NPAD) return;
    if (wv >= n) {
        ub[(size_t)wv * 64 + ln] = 0;
        return;
    }
    float di = dinv[wv];
    float acc = bf2f(xb[(size_t)wv * 64 + ln]);
    float ts = 0.f;
    int p = offs[wv], pend = offs[wv + 1];
    for (; p + 7 < pend; p += 8) {
        int s0 = esrc[p],     s1 = esrc[p + 1], s2 = esrc[p + 2], s3 = esrc[p + 3];
        int s4 = esrc[p + 4], s5 = esrc[p + 5], s6 = esrc[p + 6], s7 = esrc[p + 7];
        unsigned short h0 = xb[(size_t)s0 * 64 + ln];
        unsigned short h1 = xb[(size_t)s1 * 64 + ln];
        unsigned short h2 = xb[(size_t)s2 * 64 + ln];
        unsigned short h3 = xb[(size_t)s3 * 64 + ln];
        unsigned short h4 = xb[(size_t)s4 * 64 + ln];
        unsigned short h5 = xb[(size_t)s5 * 64 + ln];
        unsigned short h6 = xb[(size_t)s6 * 64 + ln];
        unsigned short h7 = xb[(size_t)s7 * 64 + ln];
        float w0 = dinv[s0], w1 = dinv[s1], w2 = dinv[s2], w3 = dinv[s3];
        float w4 = dinv[s4], w5 = dinv[s5], w6 = dinv[s6], w7 = dinv[s7];
        acc += bf2f(h0) + bf2f(h1) + bf2f(h2) + bf2f(h3)
             + bf2f(h4) + bf2f(h5) + bf2f(h6) + bf2f(h7);
        ts += w0 + w1 + w2 + w3 + w4 + w5 + w6 + w7;
    }
    for (; p < pend; ++p) {
        int s = esrc[p];
        acc += bf2f(xb[(size_t)s * 64 + ln]);
        ts += dinv[s];
    }
    u[(size_t)wv * 64 + ln] = acc;
    ub[(size_t)wv * 64 + ln] = f2bf(acc);
    if (ln == 0) t[wv] = di + ts;
}

// ---- fused v3 (MFMA): L^T = WaT @ ub^T (softmax -> S_T bf16 + Sf8 e4m3)
//      and Z^T = WeT @ ub^T -> Z_T bf16 directly. Block = 64 nodes (4 waves x 16). ----
#define F8ROW 520
__global__ void __launch_bounds__(256) fused_s2_kernel(
        const unsigned short* __restrict__ ub, const unsigned short* __restrict__ WaT,
        const unsigned short* __restrict__ WeT,
        const float* __restrict__ ba, const float* __restrict__ be,
        const float* __restrict__ dinv, const float* __restrict__ tsum,
        unsigned short* __restrict__ S_T, unsigned char* __restrict__ Sf8,
        unsigned short* __restrict__ Z_T, int n) {
    __shared__ float bs[512];
    __shared__ float bes[64];
    __shared__ unsigned char f8[64 * F8ROW];
    int t = threadIdx.x;
    int n0 = blockIdx.x * 64;
    {
        float b0 = (t * 2     < KK) ? ba[t * 2]     : 0.f;
        float b1 = (t * 2 + 1 < KK) ? ba[t * 2 + 1] : 0.f;
        bs[t * 2] = b0; bs[t * 2 + 1] = b1;
        if (t < 64) bes[t] = be[t];
    }
    __syncthreads();
    int wv = t >> 6, ln = t & 63;
    int nl = ln & 15;
    int g  = ln >> 4;
    int node = n0 + wv * 16 + nl;
    float sd = (node < n) ? dinv[node] : 0.f;
    float st = (node < n) ? tsum[node] : 0.f;
    const unsigned short* brow = ub + (size_t)node * 64;
    bf16x8 bf0 = *(const bf16x8*)&brow[g * 8];
    bf16x8 bf1 = *(const bf16x8*)&brow[32 + g * 8];
    f32x4 acc[32];
#pragma unroll
    for (int mt = 0; mt < 32; ++mt) {
        const unsigned short* arow = WaT + (size_t)(mt * 16 + nl) * 64;
        bf16x8 af0 = *(const bf16x8*)&arow[g * 8];
        bf16x8 af1 = *(const bf16x8*)&arow[32 + g * 8];
        f32x4 a = __builtin_amdgcn_mfma_f32_16x16x32_bf16(af0, bf0, (f32x4){0.f,0.f,0.f,0.f}, 0, 0, 0);
        acc[mt] = __builtin_amdgcn_mfma_f32_16x16x32_bf16(af1, bf1, a, 0, 0, 0);
    }
    float m = -1e30f;
#pragma unroll
    for (int mt = 0; mt < 32; ++mt) {
#pragma unroll
        for (int r = 0; r < 4; ++r) {
            int cl = mt * 16 + g * 4 + r;
            float L = sd * (acc[mt][r] + st * bs[cl]);
            if (cl >= KK) L = -1e30f;
            acc[mt][r] = L;
            m = fmaxf(m, L);
        }
    }
    m = fmaxf(m, __shfl_xor(m, 16, 64));
    m = fmaxf(m, __shfl_xor(m, 32, 64));
    float ssum = 0.f;
#pragma unroll
    for (int mt = 0; mt < 32; ++mt) {
#pragma unroll
        for (int r = 0; r < 4; ++r) {
            float e = expf(acc[mt][r] - m);
            acc[mt][r] = e;
            ssum += e;
        }
    }
    ssum += __shfl_xor(ssum, 16, 64);
    ssum += __shfl_xor(ssum, 32, 64);
    float rs = (node < n) ? (1.0f / ssum) : 0.f;
    float sc = 256.f * rs;
    unsigned char* frow = &f8[(wv * 16 + nl) * F8ROW];
#pragma unroll
    for (int mt = 0; mt < 32; ++mt) {
#pragma unroll
        for (int r = 0; r < 4; ++r) {
            int cl = mt * 16 + g * 4 + r;
            S_T[(size_t)cl * NPAD + node] = f2bf(acc[mt][r] * rs);
        }
#ifdef HAS_FP8_CVT
        int pk = __builtin_amdgcn_cvt_pk_fp8_f32(acc[mt][0] * sc, acc[mt][1] * sc, 0, false);
        pk     = __builtin_amdgcn_cvt_pk_fp8_f32(acc[mt][2] * sc, acc[mt][3] * sc, pk, true);
#else
        int pk = (int)(f32_to_fp8_slow(acc[mt][0]*sc) | (f32_to_fp8_slow(acc[mt][1]*sc) << 8) |
                       (f32_to_fp8_slow(acc[mt][2]*sc) << 16) | (f32_to_fp8_slow(acc[mt][3]*sc) << 24));
#endif
        *(unsigned*)&frow[mt * 16 + g * 4] = (unsigned)pk;
    }
#pragma unroll
    for (int mt = 0; mt < 4; ++mt) {
        const unsigned short* arow = WeT + (size_t)(mt * 16 + nl) * 64;
        bf16x8 af0 = *(const bf16x8*)&arow[g * 8];
        bf16x8 af1 = *(const bf16x8*)&arow[32 + g * 8];
        f32x4 a = __builtin_amdgcn_mfma_f32_16x16x32_bf16(af0, bf0, (f32x4){0.f,0.f,0.f,0.f}, 0, 0, 0);
        a = __builtin_amdgcn_mfma_f32_16x16x32_bf16(af1, bf1, a, 0, 0, 0);
#pragma unroll
        for (int r = 0; r < 4; ++r) {
            int ch = mt * 16 + g * 4 + r;
            float z = sd * (a[r] + st * bes[ch]);
            Z_T[(size_t)ch * NPAD + node] = f2bf(z);
        }
    }
    __syncthreads();
#pragma unroll
    for (int h = 0; h < 8; ++h) {
        int idx = t + h * 256;
        int row = idx >> 5;
        int off = (idx & 31) * 16;
        uint4 vv = *(const uint4*)&f8[row * F8ROW + off];
        int grow = n0 + row;
        if (grow < n) *(uint4*)&Sf8[(size_t)grow * KPAD + off] = vv;
    }
}

// -------- G = A^T S via in-CSR over fp8 S, TRANSPOSED bf16 out. 512 threads (8 waves). --------
#define GT_ROWS 32
__global__ void __launch_bounds__(512) g_agg_t_kernel(
        const unsigned char* __restrict__ Sf8, const int* __restrict__ offs,
        const int* __restrict__ esrc, unsigned short* __restrict__ G_T, int n) {
    __shared__ unsigned short tl[GT_ROWS * 520];
    int base = blockIdx.x * GT_ROWS;
    int wv = threadIdx.x >> 6, ln = threadIdx.x & 63;   // 8 waves
    const uint2* S2 = (const uint2*)Sf8;
#pragma unroll
    for (int i = 0; i < GT_ROWS / 8; ++i) {             // 4 nodes per wave
        int r = wv * (GT_ROWS / 8) + i;
        int node = base + r;
        float a[8] = {0.f,0.f,0.f,0.f,0.f,0.f,0.f,0.f};
        if (node < n) {
            int p = offs[node], pend = offs[node + 1];
            for (; p + 7 < pend; p += 8) {
                int s0 = esrc[p],     s1 = esrc[p + 1], s2 = esrc[p + 2], s3 = esrc[p + 3];
                int s4 = esrc[p + 4], s5 = esrc[p + 5], s6 = esrc[p + 6], s7 = esrc[p + 7];
                uint2 v0 = S2[(size_t)s0 * 64 + ln];
                uint2 v1 = S2[(size_t)s1 * 64 + ln];
                uint2 v2 = S2[(size_t)s2 * 64 + ln];
                uint2 v3 = S2[(size_t)s3 * 64 + ln];
                uint2 v4 = S2[(size_t)s4 * 64 + ln];
                uint2 v5 = S2[(size_t)s5 * 64 + ln];
                uint2 v6 = S2[(size_t)s6 * 64 + ln];
                uint2 v7 = S2[(size_t)s7 * 64 + ln];
                accf8(a, v0); accf8(a, v1); accf8(a, v2); accf8(a, v3);
                accf8(a, v4); accf8(a, v5); accf8(a, v6); accf8(a, v7);
            }
            for (; p < pend; ++p) {
                uint2 v = S2[(size_t)esrc[p] * 64 + ln];
                accf8(a, v);
            }
        }
        const float inv = 1.0f / 256.f;
        uint4 o;
        o.x = packbf(a[0] * inv, a[1] * inv); o.y = packbf(a[2] * inv, a[3] * inv);
        o.z = packbf(a[4] * inv, a[5] * inv); o.w = packbf(a[6] * inv, a[7] * inv);
        *(uint4*)&tl[r * 520 + ln * 8] = o;
    }
    __syncthreads();
    {
        int k = threadIdx.x;              // 0..511
        unsigned wb[8];
#pragma unroll
        for (int j = 0; j < 8; ++j) {
            unsigned short lo = tl[(2 * j)     * 520 + k];
            unsigned short hi = tl[(2 * j + 1) * 520 + k];
            wb[j] = ((unsigned)hi << 16) | (unsigned)lo;
        }
        unsigned wc[8];
#pragma unroll
        for (int j = 0; j < 8; ++j) {
            unsigned short lo = tl[(16 + 2 * j) * 520 + k];
            unsigned short hi = tl[(17 + 2 * j) * 520 + k];
            wc[j] = ((unsigned)hi << 16) | (unsigned)lo;
        }
        size_t ob = (size_t)k * NPAD + base;
        *(uint4*)&G_T[ob]      = make_uint4(wb[0], wb[1], wb[2], wb[3]);
        *(uint4*)&G_T[ob + 8]  = make_uint4(wb[4], wb[5], wb[6], wb[7]);
        *(uint4*)&G_T[ob + 16] = make_uint4(wc[0], wc[1], wc[2], wc[3]);
        *(uint4*)&G_T[ob + 24] = make_uint4(wc[4], wc[5], wc[6], wc[7]);
    }
}

// ---------------- MFMA TN GEMM 128x128 -> partial (next_X) ----------------
__global__ void __launch_bounds__(256) mfma_tn_kernel(
        const unsigned short* __restrict__ A_T, const unsigned short* __restrict__ B_T,
        float* __restrict__ partial, int nPer, int NBpad) {
    const int a0 = blockIdx.x * 128, b0 = blockIdx.y * 128;
    const int nbeg = blockIdx.z * nPer;
    const int nend = min(nbeg + nPer, NPAD);
    __shared__ unsigned short Al[128 * 72];
    __shared__ unsigned short Bl[128 * 72];
    const int t = threadIdx.x;
    const int ln = t & 63, wv = t >> 6;
    const int wa = (wv & 1) * 64, wb = (wv >> 1) * 64;
    const int lm = ln & 15, lk = (ln >> 4) * 8;
    f32x4 acc[4][4];
#pragma unroll
    for (int i = 0; i < 4; ++i)
#pragma unroll
        for (int j = 0; j < 4; ++j) acc[i][j] = (f32x4){0.f, 0.f, 0.f, 0.f};
    for (int nb = nbeg; nb < nend; nb += 64) {
        __syncthreads();
#pragma unroll
        for (int i = 0; i < 4; ++i) {
            int idx = t + i * 256;
            int r = idx >> 3, c8 = (idx & 7) * 8;
            uint4 va = *(const uint4*)&A_T[(size_t)(a0 + r) * NPAD + nb + c8];
            uint4 vb = *(const uint4*)&B_T[(size_t)(b0 + r) * NPAD + nb + c8];
            *(uint4*)&Al[r * 72 + c8] = va;
            *(uint4*)&Bl[r * 72 + c8] = vb;
        }
        __syncthreads();
#pragma unroll
        for (int ks = 0; ks < 64; ks += 32) {
            bf16x8 af[4], bfr[4];
#pragma unroll
            for (int i = 0; i < 4; ++i)
                af[i] = *(const bf16x8*)&Al[(wa + i * 16 + lm) * 72 + ks + lk];
#pragma unroll
            for (int j = 0; j < 4; ++j)
                bfr[j] = *(const bf16x8*)&Bl[(wb + j * 16 + lm) * 72 + ks + lk];
#pragma unroll
            for (int i = 0; i < 4; ++i)
#pragma unroll
                for (int j = 0; j < 4; ++j)
                    acc[i][j] = __builtin_amdgcn_mfma_f32_16x16x32_bf16(af[i], bfr[j], acc[i][j], 0, 0, 0);
        }
    }
    float* op = partial + (size_t)blockIdx.z * 512 * NBpad;
#pragma unroll
    for (int i = 0; i < 4; ++i) {
#pragma unroll
        for (int j = 0; j < 4; ++j) {
            int bg = b0 + wb + j * 16 + lm;
#pragma unroll
            for (int r = 0; r < 4; ++r) {
                int ag = a0 + wa + i * 16 + (ln >> 4) * 4 + r;
                op[(size_t)ag * NBpad + bg] = acc[i][j][r];
            }
        }
    }
}

// ---------------- MFMA TN GEMM 256a x 128b -> partial (next_A) ----------------
__global__ void __launch_bounds__(256) mfma_tn256_kernel(
        const unsigned short* __restrict__ A_T, const unsigned short* __restrict__ B_T,
        float* __restrict__ partial, int nPer) {
    const int a0 = blockIdx.x * 256, b0 = blockIdx.y * 128;
    const int nbeg = blockIdx.z * nPer;
    const int nend = min(nbeg + nPer, NPAD);
    __shared__ unsigned short Al[256 * 72];
    __shared__ unsigned short Bl[128 * 72];
    const int t = threadIdx.x;
    const int ln = t & 63, wv = t >> 6;
    const int wa = wv * 64;
    const int lm = ln & 15, lk = (ln >> 4) * 8;
    f32x4 acc[4][8];
#pragma unroll
    for (int i = 0; i < 4; ++i)
#pragma unroll
        for (int j = 0; j < 8; ++j) acc[i][j] = (f32x4){0.f, 0.f, 0.f, 0.f};
    for (int nb = nbeg; nb < nend; nb += 64) {
        __syncthreads();
#pragma unroll
        for (int i = 0; i < 8; ++i) {
            int idx = t + i * 256;
            int r = idx >> 3, c8 = (idx & 7) * 8;
            uint4 va = *(const uint4*)&A_T[(size_t)(a0 + r) * NPAD + nb + c8];
            *(uint4*)&Al[r * 72 + c8] = va;
        }
#pragma unroll
        for (int i = 0; i < 4; ++i) {
            int idx = t + i * 256;
            int r = idx >> 3, c8 = (idx & 7) * 8;
            uint4 vb = *(const uint4*)&B_T[(size_t)(b0 + r) * NPAD + nb + c8];
            *(uint4*)&Bl[r * 72 + c8] = vb;
        }
        __syncthreads();
#pragma unroll
        for (int ks = 0; ks < 64; ks += 32) {
            bf16x8 af[4], bfr[8];
#pragma unroll
            for (int i = 0; i < 4; ++i)
                af[i] = *(const bf16x8*)&Al[(wa + i * 16 + lm) * 72 + ks + lk];
#pragma unroll
            for (int j = 0; j < 8; ++j)
                bfr[j] = *(const bf16x8*)&Bl[(j * 16 + lm) * 72 + ks + lk];
#pragma unroll
            for (int i = 0; i < 4; ++i)
#pragma unroll
                for (int j = 0; j < 8; ++j)
                    acc[i][j] = __builtin_amdgcn_mfma_f32_16x16x32_bf16(af[i], bfr[j], acc[i][j], 0, 0, 0);
        }
    }
    float* op = partial + (size_t)blockIdx.z * 512 * 512;
#pragma unroll
    for (int i = 0; i < 4; ++i) {
#pragma unroll
        for (int j = 0; j < 8; ++j) {
            int bg = b0 + j * 16 + lm;
#pragma unroll
            for (int r = 0; r < 4; ++r) {
                int ag = a0 + wa + i * 16 + (ln >> 4) * 4 + r;
                op[(size_t)ag * 512 + bg] = acc[i][j][r];
            }
        }
    }
}

// ---------------- split-K reduce ----------------
__global__ void reduce_kernel(const float* __restrict__ partial, float* __restrict__ out,
                              int rows, int cols, int NBpad, int Z) {
    int idx = blockIdx.x * blockDim.x + threadIdx.x;
    if (idx >= rows * cols) return;
    int a = idx / cols, b = idx - a * cols;
    const float* p = partial + (size_t)a * NBpad + b;
    size_t step = (size_t)512 * NBpad;
    float s = 0.f;
    for (int z = 0; z < Z; ++z) s += p[(size_t)z * step];
    out[idx] = s;
}

extern "C" void kernel_launch(void* const* d_in, const int* in_sizes, int n_in,
                              void* d_out, int out_size, void* d_ws, size_t ws_size,
                              hipStream_t stream) {
    const float* x        = (const float*)d_in[0];
    const int*   ei       = (const int*)d_in[1];
    const float* W_embed  = (const float*)d_in[2];
    const float* b_embed  = (const float*)d_in[3];
    const float* W_assign = (const float*)d_in[4];
    const float* b_assign = (const float*)d_in[5];

    const int N = in_sizes[0] / DD;     // 50000
    const int E = in_sizes[1] / 2;      // 800000
    const int C = in_sizes[3];          // 64
    const int K = in_sizes[5];          // 500

    const int* rowv = ei;
    const int* colv = ei + E;

    char* p = (char*)d_ws;
    auto alloc = [&](size_t bytes) -> void* {
        void* r = (void*)p;
        p += (bytes + 255) & ~(size_t)255;
        return r;
    };
    int*   cnt      = (int*)alloc((size_t)2 * NS * 4);
    int*   cnt_col  = cnt;
    int*   cnt_row  = cnt + NS;
    int*   offs_col = (int*)alloc((size_t)(N + 1) * 4);
    int*   cur_col  = (int*)alloc((size_t)N * 4);
    int*   bsum     = (int*)alloc(64 * 4);
    int*   bbase    = (int*)alloc(64 * 4);
    float* dinv     = (float*)alloc((size_t)N * 4);
    float* tsum     = (float*)alloc((size_t)N * 4);
    int*   esrc     = (int*)alloc((size_t)E * 4);
    float* u        = (float*)alloc((size_t)N * DD * 4);                   // 12.8 MB
    unsigned short* xb   = (unsigned short*)alloc((size_t)N * DD * 2);
    unsigned short* ubuf = (unsigned short*)alloc((size_t)NPAD * DD * 2);
    unsigned short* WaT  = (unsigned short*)alloc((size_t)KPAD * DD * 2);
    unsigned short* WeT  = (unsigned short*)alloc((size_t)DD * DD * 2);
    unsigned char*  Sf8  = (unsigned char*)alloc((size_t)N * KPAD);
    unsigned short* S_T  = (unsigned short*)alloc((size_t)KPAD * NPAD * 2);
    unsigned short* G_T  = (unsigned short*)alloc((size_t)KPAD * NPAD * 2);
    unsigned short* Z_T  = (unsigned short*)alloc((size_t)128 * NPAD * 2);

    // split-K (nPer=1088, Z=46: 1088*46 == NPAD)
    const int nPer = 1088, ZSK = 46;
    float* partialA = (float*)alloc((size_t)ZSK * 512 * 512 * 4);          // 48.2 MB
    float* partialX = (float*)u;    // 46*512*128*4 = 12.06 MB <= 12.8 MB (u dead by then)

    float* outX = (float*)d_out;            // [500][64]
    float* outA = outX + (size_t)K * C;     // [500][500]

    const int NB = (N + 1023) / 1024;

    (void)hipMemsetAsync(cnt, 0, (size_t)2 * NS * 4, stream);

    hist_kernel<<<(E + 255) / 256, 256, 0, stream>>>(rowv, colv, cnt_row, cnt_col, E);
    scanA_kernel<<<NB, 256, 0, stream>>>(cnt_col, bsum);
    scanB_kernel<<<1, 64, 0, stream>>>(bsum, bbase, &offs_col[N], NB);
    scanC_kernel<<<NB, 256, 0, stream>>>(cnt_col, cnt_row, bbase, offs_col, cur_col, dinv, N);
    place_kernel<<<(E + 255) / 256, 256, 0, stream>>>(rowv, colv, cur_col, esrc, E);

    xscale_kernel<<<(N * 16 + 255) / 256, 256, 0, stream>>>(x, dinv, xb, N * 16);
    wprep_kernel<<<((KPAD + DD) * DD) / 256, 256, 0, stream>>>(W_assign, W_embed, WaT, WeT);

    agg_kernel<<<NPAD / 4, 256, 0, stream>>>(xb, dinv, offs_col, esrc, u, tsum, ubuf, N);

    fused_s2_kernel<<<NPAD / 64, 256, 0, stream>>>(ubuf, WaT, WeT, b_assign, b_embed,
                                                   dinv, tsum, S_T, Sf8, Z_T, N);

    g_agg_t_kernel<<<NPAD / GT_ROWS, 512, 0, stream>>>(Sf8, offs_col, esrc, G_T, N);

    // next_X = S^T @ Z : partial (in u) + reduce
    {
        dim3 g(4, 1, ZSK);
        mfma_tn_kernel<<<g, 256, 0, stream>>>(S_T, Z_T, partialX, nPer, 128);
        reduce_kernel<<<(K * C + 255) / 256, 256, 0, stream>>>(partialX, outX, K, C, 128, ZSK);
    }
    // next_A = G^T @ S : partial + reduce
    {
        dim3 g(2, 4, ZSK);
        mfma_tn256_kernel<<<g, 256, 0, stream>>>(G_T, S_T, partialA, nPer);
        reduce_kernel<<<(K * K + 255) / 256, 256, 0, stream>>>(partialA, outA, K, K, 512, ZSK);
    }
}

// Round 13
// 489.995 us; speedup vs baseline: 1.1836x; 1.0863x over previous
//
#include <hip/hip_runtime.h>
#include <hip/hip_bf16.h>
#include <math.h>

// Problem constants: N=50000, E=800000, D=64, K=500, C=64
#define DD 64
#define KK 500
#define KPAD 512
#define NPAD 50048   // N padded to multiple of 64
#define NS 50176     // N padded to multiple of 1024 (scan tiles)

typedef __attribute__((ext_vector_type(8))) short bf16x8;
typedef __attribute__((ext_vector_type(4))) float f32x4;

#if defined(__has_builtin)
#if __has_builtin(__builtin_amdgcn_cvt_pk_f32_fp8) && __has_builtin(__builtin_amdgcn_cvt_pk_fp8_f32)
#define HAS_FP8_CVT 1
#endif
#endif

__device__ inline unsigned short f2bf(float f) {
    unsigned u = __float_as_uint(f);
    u += 0x7fffu + ((u >> 16) & 1u);          // RNE
    return (unsigned short)(u >> 16);
}
__device__ inline unsigned packbf(float lo, float hi) {
    return ((unsigned)f2bf(hi) << 16) | (unsigned)f2bf(lo);
}
__device__ inline float bf2f(unsigned short h) {
    return __uint_as_float((unsigned)h << 16);
}

#ifndef HAS_FP8_CVT
__device__ inline float fp8_to_f32_slow(unsigned b) {
    unsigned s = (b >> 7) & 1, e = (b >> 3) & 15, m = b & 7;
    float v = (e == 0) ? ldexpf((float)m, -9) : ldexpf((float)(8 + m), (int)e - 10);
    return s ? -v : v;
}
__device__ inline unsigned f32_to_fp8_slow(float f) {
    unsigned sgn = (__float_as_uint(f) >> 24) & 0x80u;
    float af = fabsf(f);
    if (!(af > 0.f)) return sgn;
    if (af >= 448.f) return sgn | 0x7E;
    int e; frexpf(af, &e);
    int E = e - 1 + 7;
    if (E < 1) { unsigned q = (unsigned)rintf(ldexpf(af, 9)); return sgn | q; }
    unsigned q = (unsigned)rintf(ldexpf(af, 10 - E));
    if (q >= 16) { q = 8; E++; }
    if (E > 15 || (E == 15 && q - 8 >= 7)) return sgn | 0x7E;
    return sgn | ((unsigned)E << 3) | (q - 8);
}
#endif

__device__ inline void accf8(float* a, uint2 v) {
#ifdef HAS_FP8_CVT
    auto f0 = __builtin_amdgcn_cvt_pk_f32_fp8(v.x, false);
    a[0] += f0[0]; a[1] += f0[1];
    auto f1 = __builtin_amdgcn_cvt_pk_f32_fp8(v.x, true);
    a[2] += f1[0]; a[3] += f1[1];
    auto f2 = __builtin_amdgcn_cvt_pk_f32_fp8(v.y, false);
    a[4] += f2[0]; a[5] += f2[1];
    auto f3 = __builtin_amdgcn_cvt_pk_f32_fp8(v.y, true);
    a[6] += f3[0]; a[7] += f3[1];
#else
    a[0] += fp8_to_f32_slow(v.x & 0xff);         a[1] += fp8_to_f32_slow((v.x >> 8) & 0xff);
    a[2] += fp8_to_f32_slow((v.x >> 16) & 0xff); a[3] += fp8_to_f32_slow((v.x >> 24) & 0xff);
    a[4] += fp8_to_f32_slow(v.y & 0xff);         a[5] += fp8_to_f32_slow((v.y >> 8) & 0xff);
    a[6] += fp8_to_f32_slow((v.y >> 16) & 0xff); a[7] += fp8_to_f32_slow((v.y >> 24) & 0xff);
#endif
}

// ---------------- degree histogram ----------------
__global__ void hist_kernel(const int* __restrict__ rowv, const int* __restrict__ colv,
                            int* __restrict__ cnt_row, int* __restrict__ cnt_col, int E) {
    int e = blockIdx.x * blockDim.x + threadIdx.x;
    if (e >= E) return;
    atomicAdd(&cnt_row[rowv[e]], 1);
    atomicAdd(&cnt_col[colv[e]], 1);
}

// ---------------- hierarchical coalesced scan ----------------
__global__ void scanA_kernel(const int* __restrict__ cnt, int* __restrict__ bsum) {
    __shared__ int red[256];
    int t = threadIdx.x;
    int4 c = *(const int4*)&cnt[blockIdx.x * 1024 + t * 4];
    red[t] = c.x + c.y + c.z + c.w;
    __syncthreads();
    for (int o = 128; o > 0; o >>= 1) {
        if (t < o) red[t] += red[t + o];
        __syncthreads();
    }
    if (t == 0) bsum[blockIdx.x] = red[0];
}

__global__ void scanB_kernel(const int* __restrict__ bsum, int* __restrict__ bbase,
                             int* __restrict__ offs_n, int nb) {
    int t = threadIdx.x;
    int v = (t < nb) ? bsum[t] : 0;
    int own = v;
    for (int o = 1; o < 64; o <<= 1) {
        int w = __shfl_up(v, o, 64);
        if (t >= o) v += w;
    }
    if (t < nb) bbase[t] = v - own;
    if (t == 63) *offs_n = v;
}

__global__ void scanC_kernel(const int* __restrict__ cnt, const int* __restrict__ cnt_row,
                             const int* __restrict__ bbase, int* __restrict__ offs,
                             int* __restrict__ cur, float* __restrict__ dinv, int n) {
    __shared__ int sums[256];
    int t = threadIdx.x;
    int i0 = blockIdx.x * 1024 + t * 4;
    int4 c = *(const int4*)&cnt[i0];
    int s = c.x + c.y + c.z + c.w;
    sums[t] = s;
    __syncthreads();
    for (int o = 1; o < 256; o <<= 1) {
        int w = (t >= o) ? sums[t - o] : 0;
        __syncthreads();
        sums[t] += w;
        __syncthreads();
    }
    int base = bbase[blockIdx.x] + sums[t] - s;
    int p0 = base, p1 = base + c.x, p2 = p1 + c.y, p3 = p2 + c.z;
    if (i0 + 0 < n) { offs[i0 + 0] = p0; cur[i0 + 0] = p0; }
    if (i0 + 1 < n) { offs[i0 + 1] = p1; cur[i0 + 1] = p1; }
    if (i0 + 2 < n) { offs[i0 + 2] = p2; cur[i0 + 2] = p2; }
    if (i0 + 3 < n) { offs[i0 + 3] = p3; cur[i0 + 3] = p3; }
    int4 cr = *(const int4*)&cnt_row[i0];
    if (i0 + 0 < n) dinv[i0 + 0] = 1.0f / sqrtf((float)(cr.x + 1));
    if (i0 + 1 < n) dinv[i0 + 1] = 1.0f / sqrtf((float)(cr.y + 1));
    if (i0 + 2 < n) dinv[i0 + 2] = 1.0f / sqrtf((float)(cr.z + 1));
    if (i0 + 3 < n) dinv[i0 + 3] = 1.0f / sqrtf((float)(cr.w + 1));
}

// ---------------- in-CSR placement ----------------
__global__ void place_kernel(const int* __restrict__ rowv, const int* __restrict__ colv,
                             int* __restrict__ cur_col, int* __restrict__ esrc, int E) {
    int e = blockIdx.x * blockDim.x + threadIdx.x;
    if (e >= E) return;
    int p = atomicAdd(&cur_col[colv[e]], 1);
    esrc[p] = rowv[e];
}

// ---------------- xb = bf16(dinv[i] * x[i]) ----------------
__global__ void xscale_kernel(const float* __restrict__ x, const float* __restrict__ dinv,
                              unsigned short* __restrict__ xb, int n16) {
    int idx = blockIdx.x * blockDim.x + threadIdx.x;
    if (idx >= n16) return;
    int i = idx >> 4;
    float di = dinv[i];
    float4 v = ((const float4*)x)[idx];
    uint2 o;
    o.x = packbf(di * v.x, di * v.y);
    o.y = packbf(di * v.z, di * v.w);
    ((uint2*)xb)[idx] = o;
}

// ---------------- weight prep ----------------
__global__ void wprep_kernel(const float* __restrict__ Wa, const float* __restrict__ We,
                             unsigned short* __restrict__ WaT, unsigned short* __restrict__ WeT) {
    int idx = blockIdx.x * blockDim.x + threadIdx.x;
    if (idx < KPAD * 64) {
        int c = idx >> 6, d = idx & 63;
        float v = (c < KK) ? Wa[(size_t)d * KK + c] : 0.f;
        WaT[idx] = f2bf(v);
    } else {
        int j = idx - KPAD * 64;
        int c = j >> 6, d = j & 63;
        WeT[j] = f2bf(We[(size_t)d * 64 + c]);
    }
}

// ---- ub = bf16(xb[i] + sum_{in} xb[s]);  t[i] = dinv[i] + sum_{in} dinv[s] ----
// (fp32 u store removed: nothing reads it since Z/S consume ub)
__global__ void agg_kernel(const unsigned short* __restrict__ xb, const float* __restrict__ dinv,
                           const int* __restrict__ offs, const int* __restrict__ esrc,
                           float* __restrict__ t, unsigned short* __restrict__ ub, int n) {
    int wv = (blockIdx.x * blockDim.x + threadIdx.x) >> 6;
    int ln = threadIdx.x & 63;
    if (wv >= NPAD) return;
    if (wv >= n) {
        ub[(size_t)wv * 64 + ln] = 0;
        return;
    }
    float di = dinv[wv];
    float acc = bf2f(xb[(size_t)wv * 64 + ln]);
    float ts = 0.f;
    int p = offs[wv], pend = offs[wv + 1];
    for (; p + 7 < pend; p += 8) {
        int s0 = esrc[p],     s1 = esrc[p + 1], s2 = esrc[p + 2], s3 = esrc[p + 3];
        int s4 = esrc[p + 4], s5 = esrc[p + 5], s6 = esrc[p + 6], s7 = esrc[p + 7];
        unsigned short h0 = xb[(size_t)s0 * 64 + ln];
        unsigned short h1 = xb[(size_t)s1 * 64 + ln];
        unsigned short h2 = xb[(size_t)s2 * 64 + ln];
        unsigned short h3 = xb[(size_t)s3 * 64 + ln];
        unsigned short h4 = xb[(size_t)s4 * 64 + ln];
        unsigned short h5 = xb[(size_t)s5 * 64 + ln];
        unsigned short h6 = xb[(size_t)s6 * 64 + ln];
        unsigned short h7 = xb[(size_t)s7 * 64 + ln];
        float w0 = dinv[s0], w1 = dinv[s1], w2 = dinv[s2], w3 = dinv[s3];
        float w4 = dinv[s4], w5 = dinv[s5], w6 = dinv[s6], w7 = dinv[s7];
        acc += bf2f(h0) + bf2f(h1) + bf2f(h2) + bf2f(h3)
             + bf2f(h4) + bf2f(h5) + bf2f(h6) + bf2f(h7);
        ts += w0 + w1 + w2 + w3 + w4 + w5 + w6 + w7;
    }
    for (; p < pend; ++p) {
        int s = esrc[p];
        acc += bf2f(xb[(size_t)s * 64 + ln]);
        ts += dinv[s];
    }
    ub[(size_t)wv * 64 + ln] = f2bf(acc);
    if (ln == 0) t[wv] = di + ts;
}

// ---- fused v4 (MFMA, high-occupancy): block = 16 nodes, 4 waves split the 512 clusters
//      (wave wv: clusters wv*128..wv*128+127, acc[8] = 32 VGPRs). Cross-wave softmax via LDS.
//      Z^T: wave wv computes channels wv*16..wv*16+15. ----
#define F8ROW 520
__global__ void __launch_bounds__(256) fused_s3_kernel(
        const unsigned short* __restrict__ ub, const unsigned short* __restrict__ WaT,
        const unsigned short* __restrict__ WeT,
        const float* __restrict__ ba, const float* __restrict__ be,
        const float* __restrict__ dinv, const float* __restrict__ tsum,
        unsigned short* __restrict__ S_T, unsigned char* __restrict__ Sf8,
        unsigned short* __restrict__ Z_T, int n) {
    __shared__ float bs[512];
    __shared__ float bes[64];
    __shared__ float wmax[4][16];
    __shared__ float wsum[4][16];
    __shared__ unsigned char f8[16 * F8ROW];    // 8.3 KB fp8 node-major tile
    int t = threadIdx.x;
    int n0 = blockIdx.x * 16;
    {
        float b0 = (t * 2     < KK) ? ba[t * 2]     : 0.f;
        float b1 = (t * 2 + 1 < KK) ? ba[t * 2 + 1] : 0.f;
        bs[t * 2] = b0; bs[t * 2 + 1] = b1;
        if (t < 64) bes[t] = be[t];
    }
    __syncthreads();
    int wv = t >> 6, ln = t & 63;
    int nl = ln & 15;                 // node (C col)
    int g  = ln >> 4;                 // quad
    int node = n0 + nl;
    int kb = wv * 128;                // this wave's cluster base
    float sd = (node < n) ? dinv[node] : 0.f;
    float st = (node < n) ? tsum[node] : 0.f;
    const unsigned short* brow = ub + (size_t)node * 64;
    bf16x8 bf0 = *(const bf16x8*)&brow[g * 8];
    bf16x8 bf1 = *(const bf16x8*)&brow[32 + g * 8];
    f32x4 acc[8];
#pragma unroll
    for (int mt = 0; mt < 8; ++mt) {
        const unsigned short* arow = WaT + (size_t)(kb + mt * 16 + nl) * 64;
        bf16x8 af0 = *(const bf16x8*)&arow[g * 8];
        bf16x8 af1 = *(const bf16x8*)&arow[32 + g * 8];
        f32x4 a = __builtin_amdgcn_mfma_f32_16x16x32_bf16(af0, bf0, (f32x4){0.f,0.f,0.f,0.f}, 0, 0, 0);
        acc[mt] = __builtin_amdgcn_mfma_f32_16x16x32_bf16(af1, bf1, a, 0, 0, 0);
    }
    // bias + mask + wave-local max over this wave's 128 clusters
    float m = -1e30f;
#pragma unroll
    for (int mt = 0; mt < 8; ++mt) {
#pragma unroll
        for (int r = 0; r < 4; ++r) {
            int cl = kb + mt * 16 + g * 4 + r;
            float L = sd * (acc[mt][r] + st * bs[cl]);
            if (cl >= KK) L = -1e30f;
            acc[mt][r] = L;
            m = fmaxf(m, L);
        }
    }
    m = fmaxf(m, __shfl_xor(m, 16, 64));
    m = fmaxf(m, __shfl_xor(m, 32, 64));
    if (g == 0) wmax[wv][nl] = m;
    __syncthreads();
    m = fmaxf(fmaxf(wmax[0][nl], wmax[1][nl]), fmaxf(wmax[2][nl], wmax[3][nl]));
    float ssum = 0.f;
#pragma unroll
    for (int mt = 0; mt < 8; ++mt) {
#pragma unroll
        for (int r = 0; r < 4; ++r) {
            float e = expf(acc[mt][r] - m);
            acc[mt][r] = e;
            ssum += e;
        }
    }
    ssum += __shfl_xor(ssum, 16, 64);
    ssum += __shfl_xor(ssum, 32, 64);
    if (g == 0) wsum[wv][nl] = ssum;
    __syncthreads();
    float tot = (wsum[0][nl] + wsum[1][nl]) + (wsum[2][nl] + wsum[3][nl]);
    float rs = (node < n) ? (1.0f / tot) : 0.f;
    float sc = 256.f * rs;
    unsigned char* frow = &f8[nl * F8ROW];
#pragma unroll
    for (int mt = 0; mt < 8; ++mt) {
#pragma unroll
        for (int r = 0; r < 4; ++r) {
            int cl = kb + mt * 16 + g * 4 + r;
            S_T[(size_t)cl * NPAD + node] = f2bf(acc[mt][r] * rs);
        }
#ifdef HAS_FP8_CVT
        int pk = __builtin_amdgcn_cvt_pk_fp8_f32(acc[mt][0] * sc, acc[mt][1] * sc, 0, false);
        pk     = __builtin_amdgcn_cvt_pk_fp8_f32(acc[mt][2] * sc, acc[mt][3] * sc, pk, true);
#else
        int pk = (int)(f32_to_fp8_slow(acc[mt][0]*sc) | (f32_to_fp8_slow(acc[mt][1]*sc) << 8) |
                       (f32_to_fp8_slow(acc[mt][2]*sc) << 16) | (f32_to_fp8_slow(acc[mt][3]*sc) << 24));
#endif
        *(unsigned*)&frow[kb + mt * 16 + g * 4] = (unsigned)pk;
    }
    // embed conv: wave wv computes channels wv*16..wv*16+15
    {
        const unsigned short* arow = WeT + (size_t)(wv * 16 + nl) * 64;
        bf16x8 af0 = *(const bf16x8*)&arow[g * 8];
        bf16x8 af1 = *(const bf16x8*)&arow[32 + g * 8];
        f32x4 a = __builtin_amdgcn_mfma_f32_16x16x32_bf16(af0, bf0, (f32x4){0.f,0.f,0.f,0.f}, 0, 0, 0);
        a = __builtin_amdgcn_mfma_f32_16x16x32_bf16(af1, bf1, a, 0, 0, 0);
#pragma unroll
        for (int r = 0; r < 4; ++r) {
            int ch = wv * 16 + g * 4 + r;
            float z = sd * (a[r] + st * bes[ch]);
            Z_T[(size_t)ch * NPAD + node] = f2bf(z);
        }
    }
    __syncthreads();
    // coalesced Sf8 row stores: 16 rows x 512 B = 512 uint4
#pragma unroll
    for (int h = 0; h < 2; ++h) {
        int idx = t + h * 256;
        int row = idx >> 5;
        int off = (idx & 31) * 16;
        uint4 vv = *(const uint4*)&f8[row * F8ROW + off];
        int grow = n0 + row;
        if (grow < n) *(uint4*)&Sf8[(size_t)grow * KPAD + off] = vv;
    }
}

// -------- G = A^T S via in-CSR over fp8 S, TRANSPOSED bf16 out. 512 threads (8 waves). --------
#define GT_ROWS 32
__global__ void __launch_bounds__(512) g_agg_t_kernel(
        const unsigned char* __restrict__ Sf8, const int* __restrict__ offs,
        const int* __restrict__ esrc, unsigned short* __restrict__ G_T, int n) {
    __shared__ unsigned short tl[GT_ROWS * 520];
    int base = blockIdx.x * GT_ROWS;
    int wv = threadIdx.x >> 6, ln = threadIdx.x & 63;   // 8 waves
    const uint2* S2 = (const uint2*)Sf8;
#pragma unroll
    for (int i = 0; i < GT_ROWS / 8; ++i) {             // 4 nodes per wave
        int r = wv * (GT_ROWS / 8) + i;
        int node = base + r;
        float a[8] = {0.f,0.f,0.f,0.f,0.f,0.f,0.f,0.f};
        if (node < n) {
            int p = offs[node], pend = offs[node + 1];
            for (; p + 7 < pend; p += 8) {
                int s0 = esrc[p],     s1 = esrc[p + 1], s2 = esrc[p + 2], s3 = esrc[p + 3];
                int s4 = esrc[p + 4], s5 = esrc[p + 5], s6 = esrc[p + 6], s7 = esrc[p + 7];
                uint2 v0 = S2[(size_t)s0 * 64 + ln];
                uint2 v1 = S2[(size_t)s1 * 64 + ln];
                uint2 v2 = S2[(size_t)s2 * 64 + ln];
                uint2 v3 = S2[(size_t)s3 * 64 + ln];
                uint2 v4 = S2[(size_t)s4 * 64 + ln];
                uint2 v5 = S2[(size_t)s5 * 64 + ln];
                uint2 v6 = S2[(size_t)s6 * 64 + ln];
                uint2 v7 = S2[(size_t)s7 * 64 + ln];
                accf8(a, v0); accf8(a, v1); accf8(a, v2); accf8(a, v3);
                accf8(a, v4); accf8(a, v5); accf8(a, v6); accf8(a, v7);
            }
            for (; p < pend; ++p) {
                uint2 v = S2[(size_t)esrc[p] * 64 + ln];
                accf8(a, v);
            }
        }
        const float inv = 1.0f / 256.f;
        uint4 o;
        o.x = packbf(a[0] * inv, a[1] * inv); o.y = packbf(a[2] * inv, a[3] * inv);
        o.z = packbf(a[4] * inv, a[5] * inv); o.w = packbf(a[6] * inv, a[7] * inv);
        *(uint4*)&tl[r * 520 + ln * 8] = o;
    }
    __syncthreads();
    {
        int k = threadIdx.x;              // 0..511
        unsigned wb[8];
#pragma unroll
        for (int j = 0; j < 8; ++j) {
            unsigned short lo = tl[(2 * j)     * 520 + k];
            unsigned short hi = tl[(2 * j + 1) * 520 + k];
            wb[j] = ((unsigned)hi << 16) | (unsigned)lo;
        }
        unsigned wc[8];
#pragma unroll
        for (int j = 0; j < 8; ++j) {
            unsigned short lo = tl[(16 + 2 * j) * 520 + k];
            unsigned short hi = tl[(17 + 2 * j) * 520 + k];
            wc[j] = ((unsigned)hi << 16) | (unsigned)lo;
        }
        size_t ob = (size_t)k * NPAD + base;
        *(uint4*)&G_T[ob]      = make_uint4(wb[0], wb[1], wb[2], wb[3]);
        *(uint4*)&G_T[ob + 8]  = make_uint4(wb[4], wb[5], wb[6], wb[7]);
        *(uint4*)&G_T[ob + 16] = make_uint4(wc[0], wc[1], wc[2], wc[3]);
        *(uint4*)&G_T[ob + 24] = make_uint4(wc[4], wc[5], wc[6], wc[7]);
    }
}

// ---------------- MFMA TN GEMM 128x128 -> partial (next_X) ----------------
__global__ void __launch_bounds__(256) mfma_tn_kernel(
        const unsigned short* __restrict__ A_T, const unsigned short* __restrict__ B_T,
        float* __restrict__ partial, int nPer, int NBpad) {
    const int a0 = blockIdx.x * 128, b0 = blockIdx.y * 128;
    const int nbeg = blockIdx.z * nPer;
    const int nend = min(nbeg + nPer, NPAD);
    __shared__ unsigned short Al[128 * 72];
    __shared__ unsigned short Bl[128 * 72];
    const int t = threadIdx.x;
    const int ln = t & 63, wv = t >> 6;
    const int wa = (wv & 1) * 64, wb = (wv >> 1) * 64;
    const int lm = ln & 15, lk = (ln >> 4) * 8;
    f32x4 acc[4][4];
#pragma unroll
    for (int i = 0; i < 4; ++i)
#pragma unroll
        for (int j = 0; j < 4; ++j) acc[i][j] = (f32x4){0.f, 0.f, 0.f, 0.f};
    for (int nb = nbeg; nb < nend; nb += 64) {
        __syncthreads();
#pragma unroll
        for (int i = 0; i < 4; ++i) {
            int idx = t + i * 256;
            int r = idx >> 3, c8 = (idx & 7) * 8;
            uint4 va = *(const uint4*)&A_T[(size_t)(a0 + r) * NPAD + nb + c8];
            uint4 vb = *(const uint4*)&B_T[(size_t)(b0 + r) * NPAD + nb + c8];
            *(uint4*)&Al[r * 72 + c8] = va;
            *(uint4*)&Bl[r * 72 + c8] = vb;
        }
        __syncthreads();
#pragma unroll
        for (int ks = 0; ks < 64; ks += 32) {
            bf16x8 af[4], bfr[4];
#pragma unroll
            for (int i = 0; i < 4; ++i)
                af[i] = *(const bf16x8*)&Al[(wa + i * 16 + lm) * 72 + ks + lk];
#pragma unroll
            for (int j = 0; j < 4; ++j)
                bfr[j] = *(const bf16x8*)&Bl[(wb + j * 16 + lm) * 72 + ks + lk];
#pragma unroll
            for (int i = 0; i < 4; ++i)
#pragma unroll
                for (int j = 0; j < 4; ++j)
                    acc[i][j] = __builtin_amdgcn_mfma_f32_16x16x32_bf16(af[i], bfr[j], acc[i][j], 0, 0, 0);
        }
    }
    float* op = partial + (size_t)blockIdx.z * 512 * NBpad;
#pragma unroll
    for (int i = 0; i < 4; ++i) {
#pragma unroll
        for (int j = 0; j < 4; ++j) {
            int bg = b0 + wb + j * 16 + lm;
#pragma unroll
            for (int r = 0; r < 4; ++r) {
                int ag = a0 + wa + i * 16 + (ln >> 4) * 4 + r;
                op[(size_t)ag * NBpad + bg] = acc[i][j][r];
            }
        }
    }
}

// ---------------- MFMA TN GEMM 256a x 128b -> partial (next_A) ----------------
__global__ void __launch_bounds__(256) mfma_tn256_kernel(
        const unsigned short* __restrict__ A_T, const unsigned short* __restrict__ B_T,
        float* __restrict__ partial, int nPer) {
    const int a0 = blockIdx.x * 256, b0 = blockIdx.y * 128;
    const int nbeg = blockIdx.z * nPer;
    const int nend = min(nbeg + nPer, NPAD);
    __shared__ unsigned short Al[256 * 72];
    __shared__ unsigned short Bl[128 * 72];
    const int t = threadIdx.x;
    const int ln = t & 63, wv = t >> 6;
    const int wa = wv * 64;
    const int lm = ln & 15, lk = (ln >> 4) * 8;
    f32x4 acc[4][8];
#pragma unroll
    for (int i = 0; i < 4; ++i)
#pragma unroll
        for (int j = 0; j < 8; ++j) acc[i][j] = (f32x4){0.f, 0.f, 0.f, 0.f};
    for (int nb = nbeg; nb < nend; nb += 64) {
        __syncthreads();
#pragma unroll
        for (int i = 0; i < 8; ++i) {
            int idx = t + i * 256;
            int r = idx >> 3, c8 = (idx & 7) * 8;
            uint4 va = *(const uint4*)&A_T[(size_t)(a0 + r) * NPAD + nb + c8];
            *(uint4*)&Al[r * 72 + c8] = va;
        }
#pragma unroll
        for (int i = 0; i < 4; ++i) {
            int idx = t + i * 256;
            int r = idx >> 3, c8 = (idx & 7) * 8;
            uint4 vb = *(const uint4*)&B_T[(size_t)(b0 + r) * NPAD + nb + c8];
            *(uint4*)&Bl[r * 72 + c8] = vb;
        }
        __syncthreads();
#pragma unroll
        for (int ks = 0; ks < 64; ks += 32) {
            bf16x8 af[4], bfr[8];
#pragma unroll
            for (int i = 0; i < 4; ++i)
                af[i] = *(const bf16x8*)&Al[(wa + i * 16 + lm) * 72 + ks + lk];
#pragma unroll
            for (int j = 0; j < 8; ++j)
                bfr[j] = *(const bf16x8*)&Bl[(j * 16 + lm) * 72 + ks + lk];
#pragma unroll
            for (int i = 0; i < 4; ++i)
#pragma unroll
                for (int j = 0; j < 8; ++j)
                    acc[i][j] = __builtin_amdgcn_mfma_f32_16x16x32_bf16(af[i], bfr[j], acc[i][j], 0, 0, 0);
        }
    }
    float* op = partial + (size_t)blockIdx.z * 512 * 512;
#pragma unroll
    for (int i = 0; i < 4; ++i) {
#pragma unroll
        for (int j = 0; j < 8; ++j) {
            int bg = b0 + j * 16 + lm;
#pragma unroll
            for (int r = 0; r < 4; ++r) {
                int ag = a0 + wa + i * 16 + (ln >> 4) * 4 + r;
                op[(size_t)ag * 512 + bg] = acc[i][j][r];
            }
        }
    }
}

// ---------------- split-K reduce ----------------
__global__ void reduce_kernel(const float* __restrict__ partial, float* __restrict__ out,
                              int rows, int cols, int NBpad, int Z) {
    int idx = blockIdx.x * blockDim.x + threadIdx.x;
    if (idx >= rows * cols) return;
    int a = idx / cols, b = idx - a * cols;
    const float* p = partial + (size_t)a * NBpad + b;
    size_t step = (size_t)512 * NBpad;
    float s = 0.f;
    for (int z = 0; z < Z; ++z) s += p[(size_t)z * step];
    out[idx] = s;
}

extern "C" void kernel_launch(void* const* d_in, const int* in_sizes, int n_in,
                              void* d_out, int out_size, void* d_ws, size_t ws_size,
                              hipStream_t stream) {
    const float* x        = (const float*)d_in[0];
    const int*   ei       = (const int*)d_in[1];
    const float* W_embed  = (const float*)d_in[2];
    const float* b_embed  = (const float*)d_in[3];
    const float* W_assign = (const float*)d_in[4];
    const float* b_assign = (const float*)d_in[5];

    const int N = in_sizes[0] / DD;     // 50000
    const int E = in_sizes[1] / 2;      // 800000
    const int C = in_sizes[3];          // 64
    const int K = in_sizes[5];          // 500

    const int* rowv = ei;
    const int* colv = ei + E;

    char* p = (char*)d_ws;
    auto alloc = [&](size_t bytes) -> void* {
        void* r = (void*)p;
        p += (bytes + 255) & ~(size_t)255;
        return r;
    };
    int*   cnt      = (int*)alloc((size_t)2 * NS * 4);
    int*   cnt_col  = cnt;
    int*   cnt_row  = cnt + NS;
    int*   offs_col = (int*)alloc((size_t)(N + 1) * 4);
    int*   cur_col  = (int*)alloc((size_t)N * 4);
    int*   bsum     = (int*)alloc(64 * 4);
    int*   bbase    = (int*)alloc(64 * 4);
    float* dinv     = (float*)alloc((size_t)N * 4);
    float* tsum     = (float*)alloc((size_t)N * 4);
    int*   esrc     = (int*)alloc((size_t)E * 4);
    float* u        = (float*)alloc((size_t)N * DD * 4);                   // 12.8 MB (partialX)
    unsigned short* xb   = (unsigned short*)alloc((size_t)N * DD * 2);
    unsigned short* ubuf = (unsigned short*)alloc((size_t)NPAD * DD * 2);
    unsigned short* WaT  = (unsigned short*)alloc((size_t)KPAD * DD * 2);
    unsigned short* WeT  = (unsigned short*)alloc((size_t)DD * DD * 2);
    unsigned char*  Sf8  = (unsigned char*)alloc((size_t)N * KPAD);
    unsigned short* S_T  = (unsigned short*)alloc((size_t)KPAD * NPAD * 2);
    unsigned short* G_T  = (unsigned short*)alloc((size_t)KPAD * NPAD * 2);
    unsigned short* Z_T  = (unsigned short*)alloc((size_t)128 * NPAD * 2);

    // split-K (nPer=1088, Z=46: 1088*46 == NPAD)
    const int nPer = 1088, ZSK = 46;
    float* partialA = (float*)alloc((size_t)ZSK * 512 * 512 * 4);          // 48.2 MB
    float* partialX = (float*)u;    // 46*512*128*4 = 12.06 MB <= 12.8 MB

    float* outX = (float*)d_out;            // [500][64]
    float* outA = outX + (size_t)K * C;     // [500][500]

    const int NB = (N + 1023) / 1024;

    (void)hipMemsetAsync(cnt, 0, (size_t)2 * NS * 4, stream);

    hist_kernel<<<(E + 255) / 256, 256, 0, stream>>>(rowv, colv, cnt_row, cnt_col, E);
    scanA_kernel<<<NB, 256, 0, stream>>>(cnt_col, bsum);
    scanB_kernel<<<1, 64, 0, stream>>>(bsum, bbase, &offs_col[N], NB);
    scanC_kernel<<<NB, 256, 0, stream>>>(cnt_col, cnt_row, bbase, offs_col, cur_col, dinv, N);
    place_kernel<<<(E + 255) / 256, 256, 0, stream>>>(rowv, colv, cur_col, esrc, E);

    xscale_kernel<<<(N * 16 + 255) / 256, 256, 0, stream>>>(x, dinv, xb, N * 16);
    wprep_kernel<<<((KPAD + DD) * DD) / 256, 256, 0, stream>>>(W_assign, W_embed, WaT, WeT);

    agg_kernel<<<NPAD / 4, 256, 0, stream>>>(xb, dinv, offs_col, esrc, tsum, ubuf, N);

    fused_s3_kernel<<<NPAD / 16, 256, 0, stream>>>(ubuf, WaT, WeT, b_assign, b_embed,
                                                   dinv, tsum, S_T, Sf8, Z_T, N);

    g_agg_t_kernel<<<NPAD / GT_ROWS, 512, 0, stream>>>(Sf8, offs_col, esrc, G_T, N);

    // next_X = S^T @ Z : partial (in u) + reduce
    {
        dim3 g(4, 1, ZSK);
        mfma_tn_kernel<<<g, 256, 0, stream>>>(S_T, Z_T, partialX, nPer, 128);
        reduce_kernel<<<(K * C + 255) / 256, 256, 0, stream>>>(partialX, outX, K, C, 128, ZSK);
    }
    // next_A = G^T @ S : partial + reduce
    {
        dim3 g(2, 4, ZSK);
        mfma_tn256_kernel<<<g, 256, 0, stream>>>(G_T, S_T, partialA, nPer);
        reduce_kernel<<<(K * K + 255) / 256, 256, 0, stream>>>(partialA, outA, K, K, 512, ZSK);
    }
}

// Round 14
// 465.039 us; speedup vs baseline: 1.2471x; 1.0537x over previous
//
#include <hip/hip_runtime.h>
#include <hip/hip_bf16.h>
#include <math.h>

// Problem constants: N=50000, E=800000, D=64, K=500, C=64
#define DD 64
#define KK 500
#define KPAD 512
#define NPAD 50048   // N padded to multiple of 64
#define NS 50176     // N padded to multiple of 1024 (scan tiles)

typedef __attribute__((ext_vector_type(8))) short bf16x8;
typedef __attribute__((ext_vector_type(4))) float f32x4;

#if defined(__has_builtin)
#if __has_builtin(__builtin_amdgcn_cvt_pk_f32_fp8) && __has_builtin(__builtin_amdgcn_cvt_pk_fp8_f32)
#define HAS_FP8_CVT 1
#endif
#endif

__device__ inline unsigned short f2bf(float f) {
    unsigned u = __float_as_uint(f);
    u += 0x7fffu + ((u >> 16) & 1u);          // RNE
    return (unsigned short)(u >> 16);
}
__device__ inline unsigned packbf(float lo, float hi) {
    return ((unsigned)f2bf(hi) << 16) | (unsigned)f2bf(lo);
}
__device__ inline float bf2f(unsigned short h) {
    return __uint_as_float((unsigned)h << 16);
}

#ifndef HAS_FP8_CVT
__device__ inline float fp8_to_f32_slow(unsigned b) {
    unsigned s = (b >> 7) & 1, e = (b >> 3) & 15, m = b & 7;
    float v = (e == 0) ? ldexpf((float)m, -9) : ldexpf((float)(8 + m), (int)e - 10);
    return s ? -v : v;
}
__device__ inline unsigned f32_to_fp8_slow(float f) {
    unsigned sgn = (__float_as_uint(f) >> 24) & 0x80u;
    float af = fabsf(f);
    if (!(af > 0.f)) return sgn;
    if (af >= 448.f) return sgn | 0x7E;
    int e; frexpf(af, &e);
    int E = e - 1 + 7;
    if (E < 1) { unsigned q = (unsigned)rintf(ldexpf(af, 9)); return sgn | q; }
    unsigned q = (unsigned)rintf(ldexpf(af, 10 - E));
    if (q >= 16) { q = 8; E++; }
    if (E > 15 || (E == 15 && q - 8 >= 7)) return sgn | 0x7E;
    return sgn | ((unsigned)E << 3) | (q - 8);
}
#endif

__device__ inline void accf8(float* a, uint2 v) {
#ifdef HAS_FP8_CVT
    auto f0 = __builtin_amdgcn_cvt_pk_f32_fp8(v.x, false);
    a[0] += f0[0]; a[1] += f0[1];
    auto f1 = __builtin_amdgcn_cvt_pk_f32_fp8(v.x, true);
    a[2] += f1[0]; a[3] += f1[1];
    auto f2 = __builtin_amdgcn_cvt_pk_f32_fp8(v.y, false);
    a[4] += f2[0]; a[5] += f2[1];
    auto f3 = __builtin_amdgcn_cvt_pk_f32_fp8(v.y, true);
    a[6] += f3[0]; a[7] += f3[1];
#else
    a[0] += fp8_to_f32_slow(v.x & 0xff);         a[1] += fp8_to_f32_slow((v.x >> 8) & 0xff);
    a[2] += fp8_to_f32_slow((v.x >> 16) & 0xff); a[3] += fp8_to_f32_slow((v.x >> 24) & 0xff);
    a[4] += fp8_to_f32_slow(v.y & 0xff);         a[5] += fp8_to_f32_slow((v.y >> 8) & 0xff);
    a[6] += fp8_to_f32_slow((v.y >> 16) & 0xff); a[7] += fp8_to_f32_slow((v.y >> 24) & 0xff);
#endif
}

// ---------------- degree histogram ----------------
__global__ void hist_kernel(const int* __restrict__ rowv, const int* __restrict__ colv,
                            int* __restrict__ cnt_row, int* __restrict__ cnt_col, int E) {
    int e = blockIdx.x * blockDim.x + threadIdx.x;
    if (e >= E) return;
    atomicAdd(&cnt_row[rowv[e]], 1);
    atomicAdd(&cnt_col[colv[e]], 1);
}

// ---------------- hierarchical coalesced scan ----------------
__global__ void scanA_kernel(const int* __restrict__ cnt, int* __restrict__ bsum) {
    __shared__ int red[256];
    int t = threadIdx.x;
    int4 c = *(const int4*)&cnt[blockIdx.x * 1024 + t * 4];
    red[t] = c.x + c.y + c.z + c.w;
    __syncthreads();
    for (int o = 128; o > 0; o >>= 1) {
        if (t < o) red[t] += red[t + o];
        __syncthreads();
    }
    if (t == 0) bsum[blockIdx.x] = red[0];
}

__global__ void scanB_kernel(const int* __restrict__ bsum, int* __restrict__ bbase,
                             int* __restrict__ offs_n, int nb) {
    int t = threadIdx.x;
    int v = (t < nb) ? bsum[t] : 0;
    int own = v;
    for (int o = 1; o < 64; o <<= 1) {
        int w = __shfl_up(v, o, 64);
        if (t >= o) v += w;
    }
    if (t < nb) bbase[t] = v - own;
    if (t == 63) *offs_n = v;
}

__global__ void scanC_kernel(const int* __restrict__ cnt, const int* __restrict__ cnt_row,
                             const int* __restrict__ bbase, int* __restrict__ offs,
                             int* __restrict__ cur, float* __restrict__ dinv, int n) {
    __shared__ int sums[256];
    int t = threadIdx.x;
    int i0 = blockIdx.x * 1024 + t * 4;
    int4 c = *(const int4*)&cnt[i0];
    int s = c.x + c.y + c.z + c.w;
    sums[t] = s;
    __syncthreads();
    for (int o = 1; o < 256; o <<= 1) {
        int w = (t >= o) ? sums[t - o] : 0;
        __syncthreads();
        sums[t] += w;
        __syncthreads();
    }
    int base = bbase[blockIdx.x] + sums[t] - s;
    int p0 = base, p1 = base + c.x, p2 = p1 + c.y, p3 = p2 + c.z;
    if (i0 + 0 < n) { offs[i0 + 0] = p0; cur[i0 + 0] = p0; }
    if (i0 + 1 < n) { offs[i0 + 1] = p1; cur[i0 + 1] = p1; }
    if (i0 + 2 < n) { offs[i0 + 2] = p2; cur[i0 + 2] = p2; }
    if (i0 + 3 < n) { offs[i0 + 3] = p3; cur[i0 + 3] = p3; }
    int4 cr = *(const int4*)&cnt_row[i0];
    if (i0 + 0 < n) dinv[i0 + 0] = 1.0f / sqrtf((float)(cr.x + 1));
    if (i0 + 1 < n) dinv[i0 + 1] = 1.0f / sqrtf((float)(cr.y + 1));
    if (i0 + 2 < n) dinv[i0 + 2] = 1.0f / sqrtf((float)(cr.z + 1));
    if (i0 + 3 < n) dinv[i0 + 3] = 1.0f / sqrtf((float)(cr.w + 1));
}

// ---------------- in-CSR placement ----------------
__global__ void place_kernel(const int* __restrict__ rowv, const int* __restrict__ colv,
                             int* __restrict__ cur_col, int* __restrict__ esrc, int E) {
    int e = blockIdx.x * blockDim.x + threadIdx.x;
    if (e >= E) return;
    int p = atomicAdd(&cur_col[colv[e]], 1);
    esrc[p] = rowv[e];
}

// ---- fused prep: xb = bf16(dinv*x) (first N*16 uint2 ids) + WaT/WeT transposes ----
__global__ void prep_kernel(const float* __restrict__ x, const float* __restrict__ dinv,
                            unsigned short* __restrict__ xb,
                            const float* __restrict__ Wa, const float* __restrict__ We,
                            unsigned short* __restrict__ WaT, unsigned short* __restrict__ WeT,
                            int n16) {
    int idx = blockIdx.x * blockDim.x + threadIdx.x;
    if (idx < n16) {
        int i = idx >> 4;
        float di = dinv[i];
        float4 v = ((const float4*)x)[idx];
        uint2 o;
        o.x = packbf(di * v.x, di * v.y);
        o.y = packbf(di * v.z, di * v.w);
        ((uint2*)xb)[idx] = o;
        return;
    }
    int j = idx - n16;
    if (j < KPAD * 64) {
        int c = j >> 6, d = j & 63;
        float v = (c < KK) ? Wa[(size_t)d * KK + c] : 0.f;
        WaT[j] = f2bf(v);
    } else if (j < (KPAD + DD) * 64) {
        int k = j - KPAD * 64;
        int c = k >> 6, d = k & 63;
        WeT[k] = f2bf(We[(size_t)d * 64 + c]);
    }
}

// ---- ub = bf16(xb[i] + sum_{in} xb[s]);  t[i] = dinv[i] + sum_{in} dinv[s] ----
__global__ void agg_kernel(const unsigned short* __restrict__ xb, const float* __restrict__ dinv,
                           const int* __restrict__ offs, const int* __restrict__ esrc,
                           float* __restrict__ t, unsigned short* __restrict__ ub, int n) {
    int wv = (blockIdx.x * blockDim.x + threadIdx.x) >> 6;
    int ln = threadIdx.x & 63;
    if (wv >= NPAD) return;
    if (wv >= n) {
        ub[(size_t)wv * 64 + ln] = 0;
        return;
    }
    float di = dinv[wv];
    float acc = bf2f(xb[(size_t)wv * 64 + ln]);
    float ts = 0.f;
    int p = offs[wv], pend = offs[wv + 1];
    for (; p + 7 < pend; p += 8) {
        int s0 = esrc[p],     s1 = esrc[p + 1], s2 = esrc[p + 2], s3 = esrc[p + 3];
        int s4 = esrc[p + 4], s5 = esrc[p + 5], s6 = esrc[p + 6], s7 = esrc[p + 7];
        unsigned short h0 = xb[(size_t)s0 * 64 + ln];
        unsigned short h1 = xb[(size_t)s1 * 64 + ln];
        unsigned short h2 = xb[(size_t)s2 * 64 + ln];
        unsigned short h3 = xb[(size_t)s3 * 64 + ln];
        unsigned short h4 = xb[(size_t)s4 * 64 + ln];
        unsigned short h5 = xb[(size_t)s5 * 64 + ln];
        unsigned short h6 = xb[(size_t)s6 * 64 + ln];
        unsigned short h7 = xb[(size_t)s7 * 64 + ln];
        float w0 = dinv[s0], w1 = dinv[s1], w2 = dinv[s2], w3 = dinv[s3];
        float w4 = dinv[s4], w5 = dinv[s5], w6 = dinv[s6], w7 = dinv[s7];
        acc += bf2f(h0) + bf2f(h1) + bf2f(h2) + bf2f(h3)
             + bf2f(h4) + bf2f(h5) + bf2f(h6) + bf2f(h7);
        ts += w0 + w1 + w2 + w3 + w4 + w5 + w6 + w7;
    }
    for (; p < pend; ++p) {
        int s = esrc[p];
        acc += bf2f(xb[(size_t)s * 64 + ln]);
        ts += dinv[s];
    }
    ub[(size_t)wv * 64 + ln] = f2bf(acc);
    if (ln == 0) t[wv] = di + ts;
}

// ---- fused assign (MFMA, high-occupancy): block = 16 nodes, 4 waves split 512 clusters ----
#define F8ROW 520
__global__ void __launch_bounds__(256) fused_s3_kernel(
        const unsigned short* __restrict__ ub, const unsigned short* __restrict__ WaT,
        const unsigned short* __restrict__ WeT,
        const float* __restrict__ ba, const float* __restrict__ be,
        const float* __restrict__ dinv, const float* __restrict__ tsum,
        unsigned short* __restrict__ S_T, unsigned char* __restrict__ Sf8,
        unsigned short* __restrict__ Z_T, int n) {
    __shared__ float bs[512];
    __shared__ float bes[64];
    __shared__ float wmax[4][16];
    __shared__ float wsum[4][16];
    __shared__ unsigned char f8[16 * F8ROW];
    int t = threadIdx.x;
    int n0 = blockIdx.x * 16;
    {
        float b0 = (t * 2     < KK) ? ba[t * 2]     : 0.f;
        float b1 = (t * 2 + 1 < KK) ? ba[t * 2 + 1] : 0.f;
        bs[t * 2] = b0; bs[t * 2 + 1] = b1;
        if (t < 64) bes[t] = be[t];
    }
    __syncthreads();
    int wv = t >> 6, ln = t & 63;
    int nl = ln & 15;
    int g  = ln >> 4;
    int node = n0 + nl;
    int kb = wv * 128;
    float sd = (node < n) ? dinv[node] : 0.f;
    float st = (node < n) ? tsum[node] : 0.f;
    const unsigned short* brow = ub + (size_t)node * 64;
    bf16x8 bf0 = *(const bf16x8*)&brow[g * 8];
    bf16x8 bf1 = *(const bf16x8*)&brow[32 + g * 8];
    f32x4 acc[8];
#pragma unroll
    for (int mt = 0; mt < 8; ++mt) {
        const unsigned short* arow = WaT + (size_t)(kb + mt * 16 + nl) * 64;
        bf16x8 af0 = *(const bf16x8*)&arow[g * 8];
        bf16x8 af1 = *(const bf16x8*)&arow[32 + g * 8];
        f32x4 a = __builtin_amdgcn_mfma_f32_16x16x32_bf16(af0, bf0, (f32x4){0.f,0.f,0.f,0.f}, 0, 0, 0);
        acc[mt] = __builtin_amdgcn_mfma_f32_16x16x32_bf16(af1, bf1, a, 0, 0, 0);
    }
    float m = -1e30f;
#pragma unroll
    for (int mt = 0; mt < 8; ++mt) {
#pragma unroll
        for (int r = 0; r < 4; ++r) {
            int cl = kb + mt * 16 + g * 4 + r;
            float L = sd * (acc[mt][r] + st * bs[cl]);
            if (cl >= KK) L = -1e30f;
            acc[mt][r] = L;
            m = fmaxf(m, L);
        }
    }
    m = fmaxf(m, __shfl_xor(m, 16, 64));
    m = fmaxf(m, __shfl_xor(m, 32, 64));
    if (g == 0) wmax[wv][nl] = m;
    __syncthreads();
    m = fmaxf(fmaxf(wmax[0][nl], wmax[1][nl]), fmaxf(wmax[2][nl], wmax[3][nl]));
    float ssum = 0.f;
#pragma unroll
    for (int mt = 0; mt < 8; ++mt) {
#pragma unroll
        for (int r = 0; r < 4; ++r) {
            float e = expf(acc[mt][r] - m);
            acc[mt][r] = e;
            ssum += e;
        }
    }
    ssum += __shfl_xor(ssum, 16, 64);
    ssum += __shfl_xor(ssum, 32, 64);
    if (g == 0) wsum[wv][nl] = ssum;
    __syncthreads();
    float tot = (wsum[0][nl] + wsum[1][nl]) + (wsum[2][nl] + wsum[3][nl]);
    float rs = (node < n) ? (1.0f / tot) : 0.f;
    float sc = 256.f * rs;
    unsigned char* frow = &f8[nl * F8ROW];
#pragma unroll
    for (int mt = 0; mt < 8; ++mt) {
#pragma unroll
        for (int r = 0; r < 4; ++r) {
            int cl = kb + mt * 16 + g * 4 + r;
            S_T[(size_t)cl * NPAD + node] = f2bf(acc[mt][r] * rs);
        }
#ifdef HAS_FP8_CVT
        int pk = __builtin_amdgcn_cvt_pk_fp8_f32(acc[mt][0] * sc, acc[mt][1] * sc, 0, false);
        pk     = __builtin_amdgcn_cvt_pk_fp8_f32(acc[mt][2] * sc, acc[mt][3] * sc, pk, true);
#else
        int pk = (int)(f32_to_fp8_slow(acc[mt][0]*sc) | (f32_to_fp8_slow(acc[mt][1]*sc) << 8) |
                       (f32_to_fp8_slow(acc[mt][2]*sc) << 16) | (f32_to_fp8_slow(acc[mt][3]*sc) << 24));
#endif
        *(unsigned*)&frow[kb + mt * 16 + g * 4] = (unsigned)pk;
    }
    {
        const unsigned short* arow = WeT + (size_t)(wv * 16 + nl) * 64;
        bf16x8 af0 = *(const bf16x8*)&arow[g * 8];
        bf16x8 af1 = *(const bf16x8*)&arow[32 + g * 8];
        f32x4 a = __builtin_amdgcn_mfma_f32_16x16x32_bf16(af0, bf0, (f32x4){0.f,0.f,0.f,0.f}, 0, 0, 0);
        a = __builtin_amdgcn_mfma_f32_16x16x32_bf16(af1, bf1, a, 0, 0, 0);
#pragma unroll
        for (int r = 0; r < 4; ++r) {
            int ch = wv * 16 + g * 4 + r;
            float z = sd * (a[r] + st * bes[ch]);
            Z_T[(size_t)ch * NPAD + node] = f2bf(z);
        }
    }
    __syncthreads();
#pragma unroll
    for (int h = 0; h < 2; ++h) {
        int idx = t + h * 256;
        int row = idx >> 5;
        int off = (idx & 31) * 16;
        uint4 vv = *(const uint4*)&f8[row * F8ROW + off];
        int grow = n0 + row;
        if (grow < n) *(uint4*)&Sf8[(size_t)grow * KPAD + off] = vv;
    }
}

// -------- G = A^T S via in-CSR over fp8 S, TRANSPOSED bf16 out. 512 threads (8 waves). --------
#define GT_ROWS 32
__global__ void __launch_bounds__(512) g_agg_t_kernel(
        const unsigned char* __restrict__ Sf8, const int* __restrict__ offs,
        const int* __restrict__ esrc, unsigned short* __restrict__ G_T, int n) {
    __shared__ unsigned short tl[GT_ROWS * 520];
    int base = blockIdx.x * GT_ROWS;
    int wv = threadIdx.x >> 6, ln = threadIdx.x & 63;
    const uint2* S2 = (const uint2*)Sf8;
#pragma unroll
    for (int i = 0; i < GT_ROWS / 8; ++i) {
        int r = wv * (GT_ROWS / 8) + i;
        int node = base + r;
        float a[8] = {0.f,0.f,0.f,0.f,0.f,0.f,0.f,0.f};
        if (node < n) {
            int p = offs[node], pend = offs[node + 1];
            for (; p + 7 < pend; p += 8) {
                int s0 = esrc[p],     s1 = esrc[p + 1], s2 = esrc[p + 2], s3 = esrc[p + 3];
                int s4 = esrc[p + 4], s5 = esrc[p + 5], s6 = esrc[p + 6], s7 = esrc[p + 7];
                uint2 v0 = S2[(size_t)s0 * 64 + ln];
                uint2 v1 = S2[(size_t)s1 * 64 + ln];
                uint2 v2 = S2[(size_t)s2 * 64 + ln];
                uint2 v3 = S2[(size_t)s3 * 64 + ln];
                uint2 v4 = S2[(size_t)s4 * 64 + ln];
                uint2 v5 = S2[(size_t)s5 * 64 + ln];
                uint2 v6 = S2[(size_t)s6 * 64 + ln];
                uint2 v7 = S2[(size_t)s7 * 64 + ln];
                accf8(a, v0); accf8(a, v1); accf8(a, v2); accf8(a, v3);
                accf8(a, v4); accf8(a, v5); accf8(a, v6); accf8(a, v7);
            }
            for (; p < pend; ++p) {
                uint2 v = S2[(size_t)esrc[p] * 64 + ln];
                accf8(a, v);
            }
        }
        const float inv = 1.0f / 256.f;
        uint4 o;
        o.x = packbf(a[0] * inv, a[1] * inv); o.y = packbf(a[2] * inv, a[3] * inv);
        o.z = packbf(a[4] * inv, a[5] * inv); o.w = packbf(a[6] * inv, a[7] * inv);
        *(uint4*)&tl[r * 520 + ln * 8] = o;
    }
    __syncthreads();
    {
        int k = threadIdx.x;
        unsigned wb[8];
#pragma unroll
        for (int j = 0; j < 8; ++j) {
            unsigned short lo = tl[(2 * j)     * 520 + k];
            unsigned short hi = tl[(2 * j + 1) * 520 + k];
            wb[j] = ((unsigned)hi << 16) | (unsigned)lo;
        }
        unsigned wc[8];
#pragma unroll
        for (int j = 0; j < 8; ++j) {
            unsigned short lo = tl[(16 + 2 * j) * 520 + k];
            unsigned short hi = tl[(17 + 2 * j) * 520 + k];
            wc[j] = ((unsigned)hi << 16) | (unsigned)lo;
        }
        size_t ob = (size_t)k * NPAD + base;
        *(uint4*)&G_T[ob]      = make_uint4(wb[0], wb[1], wb[2], wb[3]);
        *(uint4*)&G_T[ob + 8]  = make_uint4(wb[4], wb[5], wb[6], wb[7]);
        *(uint4*)&G_T[ob + 16] = make_uint4(wc[0], wc[1], wc[2], wc[3]);
        *(uint4*)&G_T[ob + 24] = make_uint4(wc[4], wc[5], wc[6], wc[7]);
    }
}

// ---- combined MFMA TN GEMM: tiles 0..7 = next_A (256a x 128b, G_T x S_T -> partialA),
//      tiles 8..11 = next_X (128a x 128b, S_T x Z_T -> partialX). ----
__global__ void __launch_bounds__(256) mfma_comb_kernel(
        const unsigned short* __restrict__ S_T, const unsigned short* __restrict__ G_T,
        const unsigned short* __restrict__ Z_T,
        float* __restrict__ partialA, float* __restrict__ partialX, int nPer) {
    __shared__ unsigned short Al[256 * 72];
    __shared__ unsigned short Bl[128 * 72];
    const int tile = blockIdx.x;
    const int t = threadIdx.x;
    const int ln = t & 63, wv = t >> 6;
    const int lm = ln & 15, lk = (ln >> 4) * 8;
    const int nbeg = blockIdx.z * nPer;
    const int nend = min(nbeg + nPer, NPAD);
    if (tile < 8) {
        // ---------- next_A: 256a x 128b ----------
        const int a0 = (tile >> 2) * 256, b0 = (tile & 3) * 128;
        const int wa = wv * 64;
        f32x4 acc[4][8];
#pragma unroll
        for (int i = 0; i < 4; ++i)
#pragma unroll
            for (int j = 0; j < 8; ++j) acc[i][j] = (f32x4){0.f, 0.f, 0.f, 0.f};
        for (int nb = nbeg; nb < nend; nb += 64) {
            __syncthreads();
#pragma unroll
            for (int i = 0; i < 8; ++i) {
                int idx = t + i * 256;
                int r = idx >> 3, c8 = (idx & 7) * 8;
                uint4 va = *(const uint4*)&G_T[(size_t)(a0 + r) * NPAD + nb + c8];
                *(uint4*)&Al[r * 72 + c8] = va;
            }
#pragma unroll
            for (int i = 0; i < 4; ++i) {
                int idx = t + i * 256;
                int r = idx >> 3, c8 = (idx & 7) * 8;
                uint4 vb = *(const uint4*)&S_T[(size_t)(b0 + r) * NPAD + nb + c8];
                *(uint4*)&Bl[r * 72 + c8] = vb;
            }
            __syncthreads();
#pragma unroll
            for (int ks = 0; ks < 64; ks += 32) {
                bf16x8 af[4], bfr[8];
#pragma unroll
                for (int i = 0; i < 4; ++i)
                    af[i] = *(const bf16x8*)&Al[(wa + i * 16 + lm) * 72 + ks + lk];
#pragma unroll
                for (int j = 0; j < 8; ++j)
                    bfr[j] = *(const bf16x8*)&Bl[(j * 16 + lm) * 72 + ks + lk];
#pragma unroll
                for (int i = 0; i < 4; ++i)
#pragma unroll
                    for (int j = 0; j < 8; ++j)
                        acc[i][j] = __builtin_amdgcn_mfma_f32_16x16x32_bf16(af[i], bfr[j], acc[i][j], 0, 0, 0);
            }
        }
        float* op = partialA + (size_t)blockIdx.z * 512 * 512;
#pragma unroll
        for (int i = 0; i < 4; ++i) {
#pragma unroll
            for (int j = 0; j < 8; ++j) {
                int bg = b0 + j * 16 + lm;
#pragma unroll
                for (int r = 0; r < 4; ++r) {
                    int ag = a0 + wa + i * 16 + (ln >> 4) * 4 + r;
                    op[(size_t)ag * 512 + bg] = acc[i][j][r];
                }
            }
        }
    } else {
        // ---------- next_X: 128a x 128b (b0 = 0) ----------
        const int a0 = (tile - 8) * 128;
        const int wa = (wv & 1) * 64, wb = (wv >> 1) * 64;
        f32x4 acc[4][4];
#pragma unroll
        for (int i = 0; i < 4; ++i)
#pragma unroll
            for (int j = 0; j < 4; ++j) acc[i][j] = (f32x4){0.f, 0.f, 0.f, 0.f};
        for (int nb = nbeg; nb < nend; nb += 64) {
            __syncthreads();
#pragma unroll
            for (int i = 0; i < 4; ++i) {
                int idx = t + i * 256;
                int r = idx >> 3, c8 = (idx & 7) * 8;
                uint4 va = *(const uint4*)&S_T[(size_t)(a0 + r) * NPAD + nb + c8];
                uint4 vb = *(const uint4*)&Z_T[(size_t)r * NPAD + nb + c8];
                *(uint4*)&Al[r * 72 + c8] = va;
                *(uint4*)&Bl[r * 72 + c8] = vb;
            }
            __syncthreads();
#pragma unroll
            for (int ks = 0; ks < 64; ks += 32) {
                bf16x8 af[4], bfr[4];
#pragma unroll
                for (int i = 0; i < 4; ++i)
                    af[i] = *(const bf16x8*)&Al[(wa + i * 16 + lm) * 72 + ks + lk];
#pragma unroll
                for (int j = 0; j < 4; ++j)
                    bfr[j] = *(const bf16x8*)&Bl[(wb + j * 16 + lm) * 72 + ks + lk];
#pragma unroll
                for (int i = 0; i < 4; ++i)
#pragma unroll
                    for (int j = 0; j < 4; ++j)
                        acc[i][j] = __builtin_amdgcn_mfma_f32_16x16x32_bf16(af[i], bfr[j], acc[i][j], 0, 0, 0);
            }
        }
        float* op = partialX + (size_t)blockIdx.z * 512 * 128;
#pragma unroll
        for (int i = 0; i < 4; ++i) {
#pragma unroll
            for (int j = 0; j < 4; ++j) {
                int bg = wb + j * 16 + lm;
#pragma unroll
                for (int r = 0; r < 4; ++r) {
                    int ag = a0 + wa + i * 16 + (ln >> 4) * 4 + r;
                    op[(size_t)ag * 128 + bg] = acc[i][j][r];
                }
            }
        }
    }
}

// ---------------- combined split-K reduce (outX then outA) ----------------
__global__ void reduce2_kernel(const float* __restrict__ partialX, const float* __restrict__ partialA,
                               float* __restrict__ outX, float* __restrict__ outA, int Z) {
    int idx = blockIdx.x * blockDim.x + threadIdx.x;
    const int NX = KK * 64;          // 32000
    if (idx < NX) {
        int a = idx >> 6, b = idx & 63;
        const float* p = partialX + (size_t)a * 128 + b;
        float s = 0.f;
        for (int z = 0; z < Z; ++z) s += p[(size_t)z * 512 * 128];
        outX[idx] = s;
        return;
    }
    int j = idx - NX;
    if (j >= KK * KK) return;        // 250000
    int a = j / KK, b = j - a * KK;
    const float* p = partialA + (size_t)a * 512 + b;
    float s = 0.f;
    for (int z = 0; z < Z; ++z) s += p[(size_t)z * 512 * 512];
    outA[j] = s;
}

extern "C" void kernel_launch(void* const* d_in, const int* in_sizes, int n_in,
                              void* d_out, int out_size, void* d_ws, size_t ws_size,
                              hipStream_t stream) {
    const float* x        = (const float*)d_in[0];
    const int*   ei       = (const int*)d_in[1];
    const float* W_embed  = (const float*)d_in[2];
    const float* b_embed  = (const float*)d_in[3];
    const float* W_assign = (const float*)d_in[4];
    const float* b_assign = (const float*)d_in[5];

    const int N = in_sizes[0] / DD;     // 50000
    const int E = in_sizes[1] / 2;      // 800000
    const int C = in_sizes[3];          // 64
    const int K = in_sizes[5];          // 500

    const int* rowv = ei;
    const int* colv = ei + E;

    char* p = (char*)d_ws;
    auto alloc = [&](size_t bytes) -> void* {
        void* r = (void*)p;
        p += (bytes + 255) & ~(size_t)255;
        return r;
    };
    int*   cnt      = (int*)alloc((size_t)2 * NS * 4);
    int*   cnt_col  = cnt;
    int*   cnt_row  = cnt + NS;
    int*   offs_col = (int*)alloc((size_t)(N + 1) * 4);
    int*   cur_col  = (int*)alloc((size_t)N * 4);
    int*   bsum     = (int*)alloc(64 * 4);
    int*   bbase    = (int*)alloc(64 * 4);
    float* dinv     = (float*)alloc((size_t)N * 4);
    float* tsum     = (float*)alloc((size_t)N * 4);
    int*   esrc     = (int*)alloc((size_t)E * 4);
    float* u        = (float*)alloc((size_t)N * DD * 4);                   // 12.8 MB (partialX)
    unsigned short* xb   = (unsigned short*)alloc((size_t)N * DD * 2);
    unsigned short* ubuf = (unsigned short*)alloc((size_t)NPAD * DD * 2);
    unsigned short* WaT  = (unsigned short*)alloc((size_t)KPAD * DD * 2);
    unsigned short* WeT  = (unsigned short*)alloc((size_t)DD * DD * 2);
    unsigned char*  Sf8  = (unsigned char*)alloc((size_t)N * KPAD);
    unsigned short* S_T  = (unsigned short*)alloc((size_t)KPAD * NPAD * 2);
    unsigned short* G_T  = (unsigned short*)alloc((size_t)KPAD * NPAD * 2);
    unsigned short* Z_T  = (unsigned short*)alloc((size_t)128 * NPAD * 2);

    // split-K (nPer=2176, Z=23: 2176*23 == NPAD) — halves partial traffic vs Z=46
    const int nPer = 2176, ZSK = 23;
    float* partialA = (float*)alloc((size_t)ZSK * 512 * 512 * 4);          // 24.1 MB
    float* partialX = (float*)u;    // 23*512*128*4 = 6.03 MB <= 12.8 MB

    float* outX = (float*)d_out;            // [500][64]
    float* outA = outX + (size_t)K * C;     // [500][500]

    const int NB = (N + 1023) / 1024;

    (void)hipMemsetAsync(cnt, 0, (size_t)2 * NS * 4, stream);

    hist_kernel<<<(E + 255) / 256, 256, 0, stream>>>(rowv, colv, cnt_row, cnt_col, E);
    scanA_kernel<<<NB, 256, 0, stream>>>(cnt_col, bsum);
    scanB_kernel<<<1, 64, 0, stream>>>(bsum, bbase, &offs_col[N], NB);
    scanC_kernel<<<NB, 256, 0, stream>>>(cnt_col, cnt_row, bbase, offs_col, cur_col, dinv, N);
    place_kernel<<<(E + 255) / 256, 256, 0, stream>>>(rowv, colv, cur_col, esrc, E);

    // fused prep: xb + WaT + WeT
    {
        int total = N * 16 + (KPAD + DD) * 64;
        prep_kernel<<<(total + 255) / 256, 256, 0, stream>>>(x, dinv, xb, W_assign, W_embed,
                                                             WaT, WeT, N * 16);
    }

    agg_kernel<<<NPAD / 4, 256, 0, stream>>>(xb, dinv, offs_col, esrc, tsum, ubuf, N);

    fused_s3_kernel<<<NPAD / 16, 256, 0, stream>>>(ubuf, WaT, WeT, b_assign, b_embed,
                                                   dinv, tsum, S_T, Sf8, Z_T, N);

    g_agg_t_kernel<<<NPAD / GT_ROWS, 512, 0, stream>>>(Sf8, offs_col, esrc, G_T, N);

    // combined GEMM: next_A (tiles 0..7) + next_X (tiles 8..11)
    {
        dim3 g(12, 1, ZSK);
        mfma_comb_kernel<<<g, 256, 0, stream>>>(S_T, G_T, Z_T, partialA, partialX, nPer);
    }
    // combined reduce
    {
        int total = K * C + K * K;   // 282000
        reduce2_kernel<<<(total + 255) / 256, 256, 0, stream>>>(partialX, partialA, outX, outA, ZSK);
    }
}

// Round 15
// 459.513 us; speedup vs baseline: 1.2621x; 1.0120x over previous
//
#include <hip/hip_runtime.h>
#include <hip/hip_bf16.h>
#include <math.h>

// Problem constants: N=50000, E=800000, D=64, K=500, C=64
#define DD 64
#define KK 500
#define KPAD 512
#define NPAD 50048   // N padded to multiple of 64
#define NS 50176     // N padded to multiple of 1024 (scan tiles)

typedef __attribute__((ext_vector_type(8))) short bf16x8;
typedef __attribute__((ext_vector_type(4))) float f32x4;

#if defined(__has_builtin)
#if __has_builtin(__builtin_amdgcn_cvt_pk_f32_fp8) && __has_builtin(__builtin_amdgcn_cvt_pk_fp8_f32)
#define HAS_FP8_CVT 1
#endif
#endif

__device__ inline unsigned short f2bf(float f) {
    unsigned u = __float_as_uint(f);
    u += 0x7fffu + ((u >> 16) & 1u);          // RNE
    return (unsigned short)(u >> 16);
}
__device__ inline unsigned packbf(float lo, float hi) {
    return ((unsigned)f2bf(hi) << 16) | (unsigned)f2bf(lo);
}
__device__ inline float bf2f(unsigned short h) {
    return __uint_as_float((unsigned)h << 16);
}

#ifndef HAS_FP8_CVT
__device__ inline float fp8_to_f32_slow(unsigned b) {
    unsigned s = (b >> 7) & 1, e = (b >> 3) & 15, m = b & 7;
    float v = (e == 0) ? ldexpf((float)m, -9) : ldexpf((float)(8 + m), (int)e - 10);
    return s ? -v : v;
}
__device__ inline unsigned f32_to_fp8_slow(float f) {
    unsigned sgn = (__float_as_uint(f) >> 24) & 0x80u;
    float af = fabsf(f);
    if (!(af > 0.f)) return sgn;
    if (af >= 448.f) return sgn | 0x7E;
    int e; frexpf(af, &e);
    int E = e - 1 + 7;
    if (E < 1) { unsigned q = (unsigned)rintf(ldexpf(af, 9)); return sgn | q; }
    unsigned q = (unsigned)rintf(ldexpf(af, 10 - E));
    if (q >= 16) { q = 8; E++; }
    if (E > 15 || (E == 15 && q - 8 >= 7)) return sgn | 0x7E;
    return sgn | ((unsigned)E << 3) | (q - 8);
}
#endif

__device__ inline void accf8(float* a, uint2 v) {
#ifdef HAS_FP8_CVT
    auto f0 = __builtin_amdgcn_cvt_pk_f32_fp8(v.x, false);
    a[0] += f0[0]; a[1] += f0[1];
    auto f1 = __builtin_amdgcn_cvt_pk_f32_fp8(v.x, true);
    a[2] += f1[0]; a[3] += f1[1];
    auto f2 = __builtin_amdgcn_cvt_pk_f32_fp8(v.y, false);
    a[4] += f2[0]; a[5] += f2[1];
    auto f3 = __builtin_amdgcn_cvt_pk_f32_fp8(v.y, true);
    a[6] += f3[0]; a[7] += f3[1];
#else
    a[0] += fp8_to_f32_slow(v.x & 0xff);         a[1] += fp8_to_f32_slow((v.x >> 8) & 0xff);
    a[2] += fp8_to_f32_slow((v.x >> 16) & 0xff); a[3] += fp8_to_f32_slow((v.x >> 24) & 0xff);
    a[4] += fp8_to_f32_slow(v.y & 0xff);         a[5] += fp8_to_f32_slow((v.y >> 8) & 0xff);
    a[6] += fp8_to_f32_slow((v.y >> 16) & 0xff); a[7] += fp8_to_f32_slow((v.y >> 24) & 0xff);
#endif
}

// ---------------- degree histogram ----------------
__global__ void hist_kernel(const int* __restrict__ rowv, const int* __restrict__ colv,
                            int* __restrict__ cnt_row, int* __restrict__ cnt_col, int E) {
    int e = blockIdx.x * blockDim.x + threadIdx.x;
    if (e >= E) return;
    atomicAdd(&cnt_row[rowv[e]], 1);
    atomicAdd(&cnt_col[colv[e]], 1);
}

// ---------------- hierarchical coalesced scan ----------------
__global__ void scanA_kernel(const int* __restrict__ cnt, int* __restrict__ bsum) {
    __shared__ int red[256];
    int t = threadIdx.x;
    int4 c = *(const int4*)&cnt[blockIdx.x * 1024 + t * 4];
    red[t] = c.x + c.y + c.z + c.w;
    __syncthreads();
    for (int o = 128; o > 0; o >>= 1) {
        if (t < o) red[t] += red[t + o];
        __syncthreads();
    }
    if (t == 0) bsum[blockIdx.x] = red[0];
}

__global__ void scanB_kernel(const int* __restrict__ bsum, int* __restrict__ bbase,
                             int* __restrict__ offs_n, int nb) {
    int t = threadIdx.x;
    int v = (t < nb) ? bsum[t] : 0;
    int own = v;
    for (int o = 1; o < 64; o <<= 1) {
        int w = __shfl_up(v, o, 64);
        if (t >= o) v += w;
    }
    if (t < nb) bbase[t] = v - own;
    if (t == 63) *offs_n = v;
}

__global__ void scanC_kernel(const int* __restrict__ cnt, const int* __restrict__ cnt_row,
                             const int* __restrict__ bbase, int* __restrict__ offs,
                             int* __restrict__ cur, float* __restrict__ dinv, int n) {
    __shared__ int sums[256];
    int t = threadIdx.x;
    int i0 = blockIdx.x * 1024 + t * 4;
    int4 c = *(const int4*)&cnt[i0];
    int s = c.x + c.y + c.z + c.w;
    sums[t] = s;
    __syncthreads();
    for (int o = 1; o < 256; o <<= 1) {
        int w = (t >= o) ? sums[t - o] : 0;
        __syncthreads();
        sums[t] += w;
        __syncthreads();
    }
    int base = bbase[blockIdx.x] + sums[t] - s;
    int p0 = base, p1 = base + c.x, p2 = p1 + c.y, p3 = p2 + c.z;
    if (i0 + 0 < n) { offs[i0 + 0] = p0; cur[i0 + 0] = p0; }
    if (i0 + 1 < n) { offs[i0 + 1] = p1; cur[i0 + 1] = p1; }
    if (i0 + 2 < n) { offs[i0 + 2] = p2; cur[i0 + 2] = p2; }
    if (i0 + 3 < n) { offs[i0 + 3] = p3; cur[i0 + 3] = p3; }
    int4 cr = *(const int4*)&cnt_row[i0];
    if (i0 + 0 < n) dinv[i0 + 0] = 1.0f / sqrtf((float)(cr.x + 1));
    if (i0 + 1 < n) dinv[i0 + 1] = 1.0f / sqrtf((float)(cr.y + 1));
    if (i0 + 2 < n) dinv[i0 + 2] = 1.0f / sqrtf((float)(cr.z + 1));
    if (i0 + 3 < n) dinv[i0 + 3] = 1.0f / sqrtf((float)(cr.w + 1));
}

// ---------------- in-CSR placement ----------------
__global__ void place_kernel(const int* __restrict__ rowv, const int* __restrict__ colv,
                             int* __restrict__ cur_col, int* __restrict__ esrc, int E) {
    int e = blockIdx.x * blockDim.x + threadIdx.x;
    if (e >= E) return;
    int p = atomicAdd(&cur_col[colv[e]], 1);
    esrc[p] = rowv[e];
}

// ---- fused prep: xb = bf16(dinv*x) (first N*16 uint2 ids) + WaT/WeT transposes ----
__global__ void prep_kernel(const float* __restrict__ x, const float* __restrict__ dinv,
                            unsigned short* __restrict__ xb,
                            const float* __restrict__ Wa, const float* __restrict__ We,
                            unsigned short* __restrict__ WaT, unsigned short* __restrict__ WeT,
                            int n16) {
    int idx = blockIdx.x * blockDim.x + threadIdx.x;
    if (idx < n16) {
        int i = idx >> 4;
        float di = dinv[i];
        float4 v = ((const float4*)x)[idx];
        uint2 o;
        o.x = packbf(di * v.x, di * v.y);
        o.y = packbf(di * v.z, di * v.w);
        ((uint2*)xb)[idx] = o;
        return;
    }
    int j = idx - n16;
    if (j < KPAD * 64) {
        int c = j >> 6, d = j & 63;
        float v = (c < KK) ? Wa[(size_t)d * KK + c] : 0.f;
        WaT[j] = f2bf(v);
    } else if (j < (KPAD + DD) * 64) {
        int k = j - KPAD * 64;
        int c = k >> 6, d = k & 63;
        WeT[k] = f2bf(We[(size_t)d * 64 + c]);
    }
}

// ---- ub = bf16(xb[i] + sum_{in} xb[s]);  t[i] = dinv[i] + sum_{in} dinv[s] ----
__global__ void agg_kernel(const unsigned short* __restrict__ xb, const float* __restrict__ dinv,
                           const int* __restrict__ offs, const int* __restrict__ esrc,
                           float* __restrict__ t, unsigned short* __restrict__ ub, int n) {
    int wv = (blockIdx.x * blockDim.x + threadIdx.x) >> 6;
    int ln = threadIdx.x & 63;
    if (wv >= NPAD) return;
    if (wv >= n) {
        ub[(size_t)wv * 64 + ln] = 0;
        return;
    }
    float di = dinv[wv];
    float acc = bf2f(xb[(size_t)wv * 64 + ln]);
    float ts = 0.f;
    int p = offs[wv], pend = offs[wv + 1];
    for (; p + 7 < pend; p += 8) {
        int s0 = esrc[p],     s1 = esrc[p + 1], s2 = esrc[p + 2], s3 = esrc[p + 3];
        int s4 = esrc[p + 4], s5 = esrc[p + 5], s6 = esrc[p + 6], s7 = esrc[p + 7];
        unsigned short h0 = xb[(size_t)s0 * 64 + ln];
        unsigned short h1 = xb[(size_t)s1 * 64 + ln];
        unsigned short h2 = xb[(size_t)s2 * 64 + ln];
        unsigned short h3 = xb[(size_t)s3 * 64 + ln];
        unsigned short h4 = xb[(size_t)s4 * 64 + ln];
        unsigned short h5 = xb[(size_t)s5 * 64 + ln];
        unsigned short h6 = xb[(size_t)s6 * 64 + ln];
        unsigned short h7 = xb[(size_t)s7 * 64 + ln];
        float w0 = dinv[s0], w1 = dinv[s1], w2 = dinv[s2], w3 = dinv[s3];
        float w4 = dinv[s4], w5 = dinv[s5], w6 = dinv[s6], w7 = dinv[s7];
        acc += bf2f(h0) + bf2f(h1) + bf2f(h2) + bf2f(h3)
             + bf2f(h4) + bf2f(h5) + bf2f(h6) + bf2f(h7);
        ts += w0 + w1 + w2 + w3 + w4 + w5 + w6 + w7;
    }
    for (; p < pend; ++p) {
        int s = esrc[p];
        acc += bf2f(xb[(size_t)s * 64 + ln]);
        ts += dinv[s];
    }
    ub[(size_t)wv * 64 + ln] = f2bf(acc);
    if (ln == 0) t[wv] = di + ts;
}

// ---- fused assign (MFMA, high-occupancy): block = 16 nodes, 4 waves split 512 clusters ----
#define F8ROW 520
__global__ void __launch_bounds__(256) fused_s3_kernel(
        const unsigned short* __restrict__ ub, const unsigned short* __restrict__ WaT,
        const unsigned short* __restrict__ WeT,
        const float* __restrict__ ba, const float* __restrict__ be,
        const float* __restrict__ dinv, const float* __restrict__ tsum,
        unsigned short* __restrict__ S_T, unsigned char* __restrict__ Sf8,
        unsigned short* __restrict__ Z_T, int n) {
    __shared__ float bs[512];
    __shared__ float bes[64];
    __shared__ float wmax[4][16];
    __shared__ float wsum[4][16];
    __shared__ unsigned char f8[16 * F8ROW];
    int t = threadIdx.x;
    int n0 = blockIdx.x * 16;
    {
        float b0 = (t * 2     < KK) ? ba[t * 2]     : 0.f;
        float b1 = (t * 2 + 1 < KK) ? ba[t * 2 + 1] : 0.f;
        bs[t * 2] = b0; bs[t * 2 + 1] = b1;
        if (t < 64) bes[t] = be[t];
    }
    __syncthreads();
    int wv = t >> 6, ln = t & 63;
    int nl = ln & 15;
    int g  = ln >> 4;
    int node = n0 + nl;
    int kb = wv * 128;
    float sd = (node < n) ? dinv[node] : 0.f;
    float st = (node < n) ? tsum[node] : 0.f;
    const unsigned short* brow = ub + (size_t)node * 64;
    bf16x8 bf0 = *(const bf16x8*)&brow[g * 8];
    bf16x8 bf1 = *(const bf16x8*)&brow[32 + g * 8];
    f32x4 acc[8];
#pragma unroll
    for (int mt = 0; mt < 8; ++mt) {
        const unsigned short* arow = WaT + (size_t)(kb + mt * 16 + nl) * 64;
        bf16x8 af0 = *(const bf16x8*)&arow[g * 8];
        bf16x8 af1 = *(const bf16x8*)&arow[32 + g * 8];
        f32x4 a = __builtin_amdgcn_mfma_f32_16x16x32_bf16(af0, bf0, (f32x4){0.f,0.f,0.f,0.f}, 0, 0, 0);
        acc[mt] = __builtin_amdgcn_mfma_f32_16x16x32_bf16(af1, bf1, a, 0, 0, 0);
    }
    float m = -1e30f;
#pragma unroll
    for (int mt = 0; mt < 8; ++mt) {
#pragma unroll
        for (int r = 0; r < 4; ++r) {
            int cl = kb + mt * 16 + g * 4 + r;
            float L = sd * (acc[mt][r] + st * bs[cl]);
            if (cl >= KK) L = -1e30f;
            acc[mt][r] = L;
            m = fmaxf(m, L);
        }
    }
    m = fmaxf(m, __shfl_xor(m, 16, 64));
    m = fmaxf(m, __shfl_xor(m, 32, 64));
    if (g == 0) wmax[wv][nl] = m;
    __syncthreads();
    m = fmaxf(fmaxf(wmax[0][nl], wmax[1][nl]), fmaxf(wmax[2][nl], wmax[3][nl]));
    float ssum = 0.f;
#pragma unroll
    for (int mt = 0; mt < 8; ++mt) {
#pragma unroll
        for (int r = 0; r < 4; ++r) {
            float e = expf(acc[mt][r] - m);
            acc[mt][r] = e;
            ssum += e;
        }
    }
    ssum += __shfl_xor(ssum, 16, 64);
    ssum += __shfl_xor(ssum, 32, 64);
    if (g == 0) wsum[wv][nl] = ssum;
    __syncthreads();
    float tot = (wsum[0][nl] + wsum[1][nl]) + (wsum[2][nl] + wsum[3][nl]);
    float rs = (node < n) ? (1.0f / tot) : 0.f;
    float sc = 256.f * rs;
    unsigned char* frow = &f8[nl * F8ROW];
#pragma unroll
    for (int mt = 0; mt < 8; ++mt) {
#pragma unroll
        for (int r = 0; r < 4; ++r) {
            int cl = kb + mt * 16 + g * 4 + r;
            S_T[(size_t)cl * NPAD + node] = f2bf(acc[mt][r] * rs);
        }
#ifdef HAS_FP8_CVT
        int pk = __builtin_amdgcn_cvt_pk_fp8_f32(acc[mt][0] * sc, acc[mt][1] * sc, 0, false);
        pk     = __builtin_amdgcn_cvt_pk_fp8_f32(acc[mt][2] * sc, acc[mt][3] * sc, pk, true);
#else
        int pk = (int)(f32_to_fp8_slow(acc[mt][0]*sc) | (f32_to_fp8_slow(acc[mt][1]*sc) << 8) |
                       (f32_to_fp8_slow(acc[mt][2]*sc) << 16) | (f32_to_fp8_slow(acc[mt][3]*sc) << 24));
#endif
        *(unsigned*)&frow[kb + mt * 16 + g * 4] = (unsigned)pk;
    }
    {
        const unsigned short* arow = WeT + (size_t)(wv * 16 + nl) * 64;
        bf16x8 af0 = *(const bf16x8*)&arow[g * 8];
        bf16x8 af1 = *(const bf16x8*)&arow[32 + g * 8];
        f32x4 a = __builtin_amdgcn_mfma_f32_16x16x32_bf16(af0, bf0, (f32x4){0.f,0.f,0.f,0.f}, 0, 0, 0);
        a = __builtin_amdgcn_mfma_f32_16x16x32_bf16(af1, bf1, a, 0, 0, 0);
#pragma unroll
        for (int r = 0; r < 4; ++r) {
            int ch = wv * 16 + g * 4 + r;
            float z = sd * (a[r] + st * bes[ch]);
            Z_T[(size_t)ch * NPAD + node] = f2bf(z);
        }
    }
    __syncthreads();
#pragma unroll
    for (int h = 0; h < 2; ++h) {
        int idx = t + h * 256;
        int row = idx >> 5;
        int off = (idx & 31) * 16;
        uint4 vv = *(const uint4*)&f8[row * F8ROW + off];
        int grow = n0 + row;
        if (grow < n) *(uint4*)&Sf8[(size_t)grow * KPAD + off] = vv;
    }
}

// -------- G = A^T S via in-CSR over fp8 S, TRANSPOSED bf16 out. 512 threads (8 waves). --------
#define GT_ROWS 32
__global__ void __launch_bounds__(512) g_agg_t_kernel(
        const unsigned char* __restrict__ Sf8, const int* __restrict__ offs,
        const int* __restrict__ esrc, unsigned short* __restrict__ G_T, int n) {
    __shared__ unsigned short tl[GT_ROWS * 520];
    int base = blockIdx.x * GT_ROWS;
    int wv = threadIdx.x >> 6, ln = threadIdx.x & 63;
    const uint2* S2 = (const uint2*)Sf8;
#pragma unroll
    for (int i = 0; i < GT_ROWS / 8; ++i) {
        int r = wv * (GT_ROWS / 8) + i;
        int node = base + r;
        float a[8] = {0.f,0.f,0.f,0.f,0.f,0.f,0.f,0.f};
        if (node < n) {
            int p = offs[node], pend = offs[node + 1];
            for (; p + 7 < pend; p += 8) {
                int s0 = esrc[p],     s1 = esrc[p + 1], s2 = esrc[p + 2], s3 = esrc[p + 3];
                int s4 = esrc[p + 4], s5 = esrc[p + 5], s6 = esrc[p + 6], s7 = esrc[p + 7];
                uint2 v0 = S2[(size_t)s0 * 64 + ln];
                uint2 v1 = S2[(size_t)s1 * 64 + ln];
                uint2 v2 = S2[(size_t)s2 * 64 + ln];
                uint2 v3 = S2[(size_t)s3 * 64 + ln];
                uint2 v4 = S2[(size_t)s4 * 64 + ln];
                uint2 v5 = S2[(size_t)s5 * 64 + ln];
                uint2 v6 = S2[(size_t)s6 * 64 + ln];
                uint2 v7 = S2[(size_t)s7 * 64 + ln];
                accf8(a, v0); accf8(a, v1); accf8(a, v2); accf8(a, v3);
                accf8(a, v4); accf8(a, v5); accf8(a, v6); accf8(a, v7);
            }
            for (; p < pend; ++p) {
                uint2 v = S2[(size_t)esrc[p] * 64 + ln];
                accf8(a, v);
            }
        }
        const float inv = 1.0f / 256.f;
        uint4 o;
        o.x = packbf(a[0] * inv, a[1] * inv); o.y = packbf(a[2] * inv, a[3] * inv);
        o.z = packbf(a[4] * inv, a[5] * inv); o.w = packbf(a[6] * inv, a[7] * inv);
        *(uint4*)&tl[r * 520 + ln * 8] = o;
    }
    __syncthreads();
    {
        int k = threadIdx.x;
        unsigned wb[8];
#pragma unroll
        for (int j = 0; j < 8; ++j) {
            unsigned short lo = tl[(2 * j)     * 520 + k];
            unsigned short hi = tl[(2 * j + 1) * 520 + k];
            wb[j] = ((unsigned)hi << 16) | (unsigned)lo;
        }
        unsigned wc[8];
#pragma unroll
        for (int j = 0; j < 8; ++j) {
            unsigned short lo = tl[(16 + 2 * j) * 520 + k];
            unsigned short hi = tl[(17 + 2 * j) * 520 + k];
            wc[j] = ((unsigned)hi << 16) | (unsigned)lo;
        }
        size_t ob = (size_t)k * NPAD + base;
        *(uint4*)&G_T[ob]      = make_uint4(wb[0], wb[1], wb[2], wb[3]);
        *(uint4*)&G_T[ob + 8]  = make_uint4(wb[4], wb[5], wb[6], wb[7]);
        *(uint4*)&G_T[ob + 16] = make_uint4(wc[0], wc[1], wc[2], wc[3]);
        *(uint4*)&G_T[ob + 24] = make_uint4(wc[4], wc[5], wc[6], wc[7]);
    }
}

// ---- combined MFMA TN GEMM: tiles 0..7 = next_A (256a x 128b, G_T x S_T -> partialA),
//      tiles 8..11 = next_X (128a x 128b, S_T x Z_T -> partialX). ----
__global__ void __launch_bounds__(256) mfma_comb_kernel(
        const unsigned short* __restrict__ S_T, const unsigned short* __restrict__ G_T,
        const unsigned short* __restrict__ Z_T,
        float* __restrict__ partialA, float* __restrict__ partialX, int nPer) {
    __shared__ unsigned short Al[256 * 72];
    __shared__ unsigned short Bl[128 * 72];
    const int tile = blockIdx.x;
    const int t = threadIdx.x;
    const int ln = t & 63, wv = t >> 6;
    const int lm = ln & 15, lk = (ln >> 4) * 8;
    const int nbeg = blockIdx.z * nPer;
    const int nend = min(nbeg + nPer, NPAD);
    if (tile < 8) {
        // ---------- next_A: 256a x 128b ----------
        const int a0 = (tile >> 2) * 256, b0 = (tile & 3) * 128;
        const int wa = wv * 64;
        f32x4 acc[4][8];
#pragma unroll
        for (int i = 0; i < 4; ++i)
#pragma unroll
            for (int j = 0; j < 8; ++j) acc[i][j] = (f32x4){0.f, 0.f, 0.f, 0.f};
        for (int nb = nbeg; nb < nend; nb += 64) {
            __syncthreads();
#pragma unroll
            for (int i = 0; i < 8; ++i) {
                int idx = t + i * 256;
                int r = idx >> 3, c8 = (idx & 7) * 8;
                uint4 va = *(const uint4*)&G_T[(size_t)(a0 + r) * NPAD + nb + c8];
                *(uint4*)&Al[r * 72 + c8] = va;
            }
#pragma unroll
            for (int i = 0; i < 4; ++i) {
                int idx = t + i * 256;
                int r = idx >> 3, c8 = (idx & 7) * 8;
                uint4 vb = *(const uint4*)&S_T[(size_t)(b0 + r) * NPAD + nb + c8];
                *(uint4*)&Bl[r * 72 + c8] = vb;
            }
            __syncthreads();
#pragma unroll
            for (int ks = 0; ks < 64; ks += 32) {
                bf16x8 af[4], bfr[8];
#pragma unroll
                for (int i = 0; i < 4; ++i)
                    af[i] = *(const bf16x8*)&Al[(wa + i * 16 + lm) * 72 + ks + lk];
#pragma unroll
                for (int j = 0; j < 8; ++j)
                    bfr[j] = *(const bf16x8*)&Bl[(j * 16 + lm) * 72 + ks + lk];
#pragma unroll
                for (int i = 0; i < 4; ++i)
#pragma unroll
                    for (int j = 0; j < 8; ++j)
                        acc[i][j] = __builtin_amdgcn_mfma_f32_16x16x32_bf16(af[i], bfr[j], acc[i][j], 0, 0, 0);
            }
        }
        float* op = partialA + (size_t)blockIdx.z * 512 * 512;
#pragma unroll
        for (int i = 0; i < 4; ++i) {
#pragma unroll
            for (int j = 0; j < 8; ++j) {
                int bg = b0 + j * 16 + lm;
#pragma unroll
                for (int r = 0; r < 4; ++r) {
                    int ag = a0 + wa + i * 16 + (ln >> 4) * 4 + r;
                    op[(size_t)ag * 512 + bg] = acc[i][j][r];
                }
            }
        }
    } else {
        // ---------- next_X: 128a x 128b (b0 = 0) ----------
        const int a0 = (tile - 8) * 128;
        const int wa = (wv & 1) * 64, wb = (wv >> 1) * 64;
        f32x4 acc[4][4];
#pragma unroll
        for (int i = 0; i < 4; ++i)
#pragma unroll
            for (int j = 0; j < 4; ++j) acc[i][j] = (f32x4){0.f, 0.f, 0.f, 0.f};
        for (int nb = nbeg; nb < nend; nb += 64) {
            __syncthreads();
#pragma unroll
            for (int i = 0; i < 4; ++i) {
                int idx = t + i * 256;
                int r = idx >> 3, c8 = (idx & 7) * 8;
                uint4 va = *(const uint4*)&S_T[(size_t)(a0 + r) * NPAD + nb + c8];
                uint4 vb = *(const uint4*)&Z_T[(size_t)r * NPAD + nb + c8];
                *(uint4*)&Al[r * 72 + c8] = va;
                *(uint4*)&Bl[r * 72 + c8] = vb;
            }
            __syncthreads();
#pragma unroll
            for (int ks = 0; ks < 64; ks += 32) {
                bf16x8 af[4], bfr[4];
#pragma unroll
                for (int i = 0; i < 4; ++i)
                    af[i] = *(const bf16x8*)&Al[(wa + i * 16 + lm) * 72 + ks + lk];
#pragma unroll
                for (int j = 0; j < 4; ++j)
                    bfr[j] = *(const bf16x8*)&Bl[(wb + j * 16 + lm) * 72 + ks + lk];
#pragma unroll
                for (int i = 0; i < 4; ++i)
#pragma unroll
                    for (int j = 0; j < 4; ++j)
                        acc[i][j] = __builtin_amdgcn_mfma_f32_16x16x32_bf16(af[i], bfr[j], acc[i][j], 0, 0, 0);
            }
        }
        float* op = partialX + (size_t)blockIdx.z * 512 * 128;
#pragma unroll
        for (int i = 0; i < 4; ++i) {
#pragma unroll
            for (int j = 0; j < 4; ++j) {
                int bg = wb + j * 16 + lm;
#pragma unroll
                for (int r = 0; r < 4; ++r) {
                    int ag = a0 + wa + i * 16 + (ln >> 4) * 4 + r;
                    op[(size_t)ag * 128 + bg] = acc[i][j][r];
                }
            }
        }
    }
}

// ---------------- combined split-K reduce (outX then outA) ----------------
__global__ void reduce2_kernel(const float* __restrict__ partialX, const float* __restrict__ partialA,
                               float* __restrict__ outX, float* __restrict__ outA, int Z) {
    int idx = blockIdx.x * blockDim.x + threadIdx.x;
    const int NX = KK * 64;          // 32000
    if (idx < NX) {
        int a = idx >> 6, b = idx & 63;
        const float* p = partialX + (size_t)a * 128 + b;
        float s = 0.f;
        for (int z = 0; z < Z; ++z) s += p[(size_t)z * 512 * 128];
        outX[idx] = s;
        return;
    }
    int j = idx - NX;
    if (j >= KK * KK) return;        // 250000
    int a = j / KK, b = j - a * KK;
    const float* p = partialA + (size_t)a * 512 + b;
    float s = 0.f;
    for (int z = 0; z < Z; ++z) s += p[(size_t)z * 512 * 512];
    outA[j] = s;
}

extern "C" void kernel_launch(void* const* d_in, const int* in_sizes, int n_in,
                              void* d_out, int out_size, void* d_ws, size_t ws_size,
                              hipStream_t stream) {
    const float* x        = (const float*)d_in[0];
    const int*   ei       = (const int*)d_in[1];
    const float* W_embed  = (const float*)d_in[2];
    const float* b_embed  = (const float*)d_in[3];
    const float* W_assign = (const float*)d_in[4];
    const float* b_assign = (const float*)d_in[5];

    const int N = in_sizes[0] / DD;     // 50000
    const int E = in_sizes[1] / 2;      // 800000
    const int C = in_sizes[3];          // 64
    const int K = in_sizes[5];          // 500

    const int* rowv = ei;
    const int* colv = ei + E;

    char* p = (char*)d_ws;
    auto alloc = [&](size_t bytes) -> void* {
        void* r = (void*)p;
        p += (bytes + 255) & ~(size_t)255;
        return r;
    };
    int*   cnt      = (int*)alloc((size_t)2 * NS * 4);
    int*   cnt_col  = cnt;
    int*   cnt_row  = cnt + NS;
    int*   offs_col = (int*)alloc((size_t)(N + 1) * 4);
    int*   cur_col  = (int*)alloc((size_t)N * 4);
    int*   bsum     = (int*)alloc(64 * 4);
    int*   bbase    = (int*)alloc(64 * 4);
    float* dinv     = (float*)alloc((size_t)N * 4);
    float* tsum     = (float*)alloc((size_t)N * 4);
    int*   esrc     = (int*)alloc((size_t)E * 4);
    float* u        = (float*)alloc((size_t)N * DD * 4);                   // 12.8 MB (partialX)
    unsigned short* xb   = (unsigned short*)alloc((size_t)N * DD * 2);
    unsigned short* ubuf = (unsigned short*)alloc((size_t)NPAD * DD * 2);
    unsigned short* WaT  = (unsigned short*)alloc((size_t)KPAD * DD * 2);
    unsigned short* WeT  = (unsigned short*)alloc((size_t)DD * DD * 2);
    unsigned char*  Sf8  = (unsigned char*)alloc((size_t)N * KPAD);
    unsigned short* S_T  = (unsigned short*)alloc((size_t)KPAD * NPAD * 2);
    unsigned short* G_T  = (unsigned short*)alloc((size_t)KPAD * NPAD * 2);
    unsigned short* Z_T  = (unsigned short*)alloc((size_t)128 * NPAD * 2);

    // split-K (nPer=1088, Z=46: 1088*46 == NPAD) — 552 blocks for occupancy
    const int nPer = 1088, ZSK = 46;
    float* partialA = (float*)alloc((size_t)ZSK * 512 * 512 * 4);          // 48.2 MB
    float* partialX = (float*)u;    // 46*512*128*4 = 12.06 MB <= 12.8 MB

    float* outX = (float*)d_out;            // [500][64]
    float* outA = outX + (size_t)K * C;     // [500][500]

    const int NB = (N + 1023) / 1024;

    (void)hipMemsetAsync(cnt, 0, (size_t)2 * NS * 4, stream);

    hist_kernel<<<(E + 255) / 256, 256, 0, stream>>>(rowv, colv, cnt_row, cnt_col, E);
    scanA_kernel<<<NB, 256, 0, stream>>>(cnt_col, bsum);
    scanB_kernel<<<1, 64, 0, stream>>>(bsum, bbase, &offs_col[N], NB);
    scanC_kernel<<<NB, 256, 0, stream>>>(cnt_col, cnt_row, bbase, offs_col, cur_col, dinv, N);
    place_kernel<<<(E + 255) / 256, 256, 0, stream>>>(rowv, colv, cur_col, esrc, E);

    // fused prep: xb + WaT + WeT
    {
        int total = N * 16 + (KPAD + DD) * 64;
        prep_kernel<<<(total + 255) / 256, 256, 0, stream>>>(x, dinv, xb, W_assign, W_embed,
                                                             WaT, WeT, N * 16);
    }

    agg_kernel<<<NPAD / 4, 256, 0, stream>>>(xb, dinv, offs_col, esrc, tsum, ubuf, N);

    fused_s3_kernel<<<NPAD / 16, 256, 0, stream>>>(ubuf, WaT, WeT, b_assign, b_embed,
                                                   dinv, tsum, S_T, Sf8, Z_T, N);

    g_agg_t_kernel<<<NPAD / GT_ROWS, 512, 0, stream>>>(Sf8, offs_col, esrc, G_T, N);

    // combined GEMM: next_A (tiles 0..7) + next_X (tiles 8..11)
    {
        dim3 g(12, 1, ZSK);
        mfma_comb_kernel<<<g, 256, 0, stream>>>(S_T, G_T, Z_T, partialA, partialX, nPer);
    }
    // combined reduce
    {
        int total = K * C + K * K;   // 282000
        reduce2_kernel<<<(total + 255) / 256, 256, 0, stream>>>(partialX, partialA, outX, outA, ZSK);
    }
}

// Round 16
// 429.606 us; speedup vs baseline: 1.3499x; 1.0696x over previous
//
#include <hip/hip_runtime.h>
#include <hip/hip_bf16.h>
#include <math.h>

// Problem constants: N=50000, E=800000, D=64, K=500, C=64
#define DD 64
#define KK 500
#define KPAD 512
#define NPAD 50048   // N padded to multiple of 64
#define NS 50176     // N padded to multiple of 1024 (scan tiles)

typedef __attribute__((ext_vector_type(8))) short bf16x8;
typedef __attribute__((ext_vector_type(4))) float f32x4;

#if defined(__has_builtin)
#if __has_builtin(__builtin_amdgcn_cvt_pk_f32_fp8) && __has_builtin(__builtin_amdgcn_cvt_pk_fp8_f32)
#define HAS_FP8_CVT 1
#endif
#endif

__device__ inline unsigned short f2bf(float f) {
    unsigned u = __float_as_uint(f);
    u += 0x7fffu + ((u >> 16) & 1u);          // RNE
    return (unsigned short)(u >> 16);
}
__device__ inline unsigned packbf(float lo, float hi) {
    return ((unsigned)f2bf(hi) << 16) | (unsigned)f2bf(lo);
}
__device__ inline float bf2f(unsigned short h) {
    return __uint_as_float((unsigned)h << 16);
}

#ifndef HAS_FP8_CVT
__device__ inline float fp8_to_f32_slow(unsigned b) {
    unsigned s = (b >> 7) & 1, e = (b >> 3) & 15, m = b & 7;
    float v = (e == 0) ? ldexpf((float)m, -9) : ldexpf((float)(8 + m), (int)e - 10);
    return s ? -v : v;
}
__device__ inline unsigned f32_to_fp8_slow(float f) {
    unsigned sgn = (__float_as_uint(f) >> 24) & 0x80u;
    float af = fabsf(f);
    if (!(af > 0.f)) return sgn;
    if (af >= 448.f) return sgn | 0x7E;
    int e; frexpf(af, &e);
    int E = e - 1 + 7;
    if (E < 1) { unsigned q = (unsigned)rintf(ldexpf(af, 9)); return sgn | q; }
    unsigned q = (unsigned)rintf(ldexpf(af, 10 - E));
    if (q >= 16) { q = 8; E++; }
    if (E > 15 || (E == 15 && q - 8 >= 7)) return sgn | 0x7E;
    return sgn | ((unsigned)E << 3) | (q - 8);
}
#endif

__device__ inline void accf8(float* a, uint2 v) {
#ifdef HAS_FP8_CVT
    auto f0 = __builtin_amdgcn_cvt_pk_f32_fp8(v.x, false);
    a[0] += f0[0]; a[1] += f0[1];
    auto f1 = __builtin_amdgcn_cvt_pk_f32_fp8(v.x, true);
    a[2] += f1[0]; a[3] += f1[1];
    auto f2 = __builtin_amdgcn_cvt_pk_f32_fp8(v.y, false);
    a[4] += f2[0]; a[5] += f2[1];
    auto f3 = __builtin_amdgcn_cvt_pk_f32_fp8(v.y, true);
    a[6] += f3[0]; a[7] += f3[1];
#else
    a[0] += fp8_to_f32_slow(v.x & 0xff);         a[1] += fp8_to_f32_slow((v.x >> 8) & 0xff);
    a[2] += fp8_to_f32_slow((v.x >> 16) & 0xff); a[3] += fp8_to_f32_slow((v.x >> 24) & 0xff);
    a[4] += fp8_to_f32_slow(v.y & 0xff);         a[5] += fp8_to_f32_slow((v.y >> 8) & 0xff);
    a[6] += fp8_to_f32_slow((v.y >> 16) & 0xff); a[7] += fp8_to_f32_slow((v.y >> 24) & 0xff);
#endif
}

// ---------------- degree histogram ----------------
__global__ void hist_kernel(const int* __restrict__ rowv, const int* __restrict__ colv,
                            int* __restrict__ cnt_row, int* __restrict__ cnt_col, int E) {
    int e = blockIdx.x * blockDim.x + threadIdx.x;
    if (e >= E) return;
    atomicAdd(&cnt_row[rowv[e]], 1);
    atomicAdd(&cnt_col[colv[e]], 1);
}

// ---------------- hierarchical coalesced scan ----------------
__global__ void scanA_kernel(const int* __restrict__ cnt, int* __restrict__ bsum) {
    __shared__ int red[256];
    int t = threadIdx.x;
    int4 c = *(const int4*)&cnt[blockIdx.x * 1024 + t * 4];
    red[t] = c.x + c.y + c.z + c.w;
    __syncthreads();
    for (int o = 128; o > 0; o >>= 1) {
        if (t < o) red[t] += red[t + o];
        __syncthreads();
    }
    if (t == 0) bsum[blockIdx.x] = red[0];
}

__global__ void scanB_kernel(const int* __restrict__ bsum, int* __restrict__ bbase,
                             int* __restrict__ offs_n, int nb) {
    int t = threadIdx.x;
    int v = (t < nb) ? bsum[t] : 0;
    int own = v;
    for (int o = 1; o < 64; o <<= 1) {
        int w = __shfl_up(v, o, 64);
        if (t >= o) v += w;
    }
    if (t < nb) bbase[t] = v - own;
    if (t == 63) *offs_n = v;
}

__global__ void scanC_kernel(const int* __restrict__ cnt, const int* __restrict__ cnt_row,
                             const int* __restrict__ bbase, int* __restrict__ offs,
                             int* __restrict__ cur, float* __restrict__ dinv, int n) {
    __shared__ int sums[256];
    int t = threadIdx.x;
    int i0 = blockIdx.x * 1024 + t * 4;
    int4 c = *(const int4*)&cnt[i0];
    int s = c.x + c.y + c.z + c.w;
    sums[t] = s;
    __syncthreads();
    for (int o = 1; o < 256; o <<= 1) {
        int w = (t >= o) ? sums[t - o] : 0;
        __syncthreads();
        sums[t] += w;
        __syncthreads();
    }
    int base = bbase[blockIdx.x] + sums[t] - s;
    int p0 = base, p1 = base + c.x, p2 = p1 + c.y, p3 = p2 + c.z;
    if (i0 + 0 < n) { offs[i0 + 0] = p0; cur[i0 + 0] = p0; }
    if (i0 + 1 < n) { offs[i0 + 1] = p1; cur[i0 + 1] = p1; }
    if (i0 + 2 < n) { offs[i0 + 2] = p2; cur[i0 + 2] = p2; }
    if (i0 + 3 < n) { offs[i0 + 3] = p3; cur[i0 + 3] = p3; }
    int4 cr = *(const int4*)&cnt_row[i0];
    if (i0 + 0 < n) dinv[i0 + 0] = 1.0f / sqrtf((float)(cr.x + 1));
    if (i0 + 1 < n) dinv[i0 + 1] = 1.0f / sqrtf((float)(cr.y + 1));
    if (i0 + 2 < n) dinv[i0 + 2] = 1.0f / sqrtf((float)(cr.z + 1));
    if (i0 + 3 < n) dinv[i0 + 3] = 1.0f / sqrtf((float)(cr.w + 1));
}

// ---------------- in-CSR placement ----------------
__global__ void place_kernel(const int* __restrict__ rowv, const int* __restrict__ colv,
                             int* __restrict__ cur_col, int* __restrict__ esrc, int E) {
    int e = blockIdx.x * blockDim.x + threadIdx.x;
    if (e >= E) return;
    int p = atomicAdd(&cur_col[colv[e]], 1);
    esrc[p] = rowv[e];
}

// ---- fused prep: xb = bf16(dinv*x) + WaT/WeT transposes ----
__global__ void prep_kernel(const float* __restrict__ x, const float* __restrict__ dinv,
                            unsigned short* __restrict__ xb,
                            const float* __restrict__ Wa, const float* __restrict__ We,
                            unsigned short* __restrict__ WaT, unsigned short* __restrict__ WeT,
                            int n16) {
    int idx = blockIdx.x * blockDim.x + threadIdx.x;
    if (idx < n16) {
        int i = idx >> 4;
        float di = dinv[i];
        float4 v = ((const float4*)x)[idx];
        uint2 o;
        o.x = packbf(di * v.x, di * v.y);
        o.y = packbf(di * v.z, di * v.w);
        ((uint2*)xb)[idx] = o;
        return;
    }
    int j = idx - n16;
    if (j < KPAD * 64) {
        int c = j >> 6, d = j & 63;
        float v = (c < KK) ? Wa[(size_t)d * KK + c] : 0.f;
        WaT[j] = f2bf(v);
    } else if (j < (KPAD + DD) * 64) {
        int k = j - KPAD * 64;
        int c = k >> 6, d = k & 63;
        WeT[k] = f2bf(We[(size_t)d * 64 + c]);
    }
}

// ---- ub = bf16(xb[i] + sum_{in} xb[s]);  t[i] = dinv[i] + sum_{in} dinv[s] ----
__global__ void agg_kernel(const unsigned short* __restrict__ xb, const float* __restrict__ dinv,
                           const int* __restrict__ offs, const int* __restrict__ esrc,
                           float* __restrict__ t, unsigned short* __restrict__ ub, int n) {
    int wv = (blockIdx.x * blockDim.x + threadIdx.x) >> 6;
    int ln = threadIdx.x & 63;
    if (wv >= NPAD) return;
    if (wv >= n) {
        ub[(size_t)wv * 64 + ln] = 0;
        return;
    }
    float di = dinv[wv];
    float acc = bf2f(xb[(size_t)wv * 64 + ln]);
    float ts = 0.f;
    int p = offs[wv], pend = offs[wv + 1];
    for (; p + 7 < pend; p += 8) {
        int s0 = esrc[p],     s1 = esrc[p + 1], s2 = esrc[p + 2], s3 = esrc[p + 3];
        int s4 = esrc[p + 4], s5 = esrc[p + 5], s6 = esrc[p + 6], s7 = esrc[p + 7];
        unsigned short h0 = xb[(size_t)s0 * 64 + ln];
        unsigned short h1 = xb[(size_t)s1 * 64 + ln];
        unsigned short h2 = xb[(size_t)s2 * 64 + ln];
        unsigned short h3 = xb[(size_t)s3 * 64 + ln];
        unsigned short h4 = xb[(size_t)s4 * 64 + ln];
        unsigned short h5 = xb[(size_t)s5 * 64 + ln];
        unsigned short h6 = xb[(size_t)s6 * 64 + ln];
        unsigned short h7 = xb[(size_t)s7 * 64 + ln];
        float w0 = dinv[s0], w1 = dinv[s1], w2 = dinv[s2], w3 = dinv[s3];
        float w4 = dinv[s4], w5 = dinv[s5], w6 = dinv[s6], w7 = dinv[s7];
        acc += bf2f(h0) + bf2f(h1) + bf2f(h2) + bf2f(h3)
             + bf2f(h4) + bf2f(h5) + bf2f(h6) + bf2f(h7);
        ts += w0 + w1 + w2 + w3 + w4 + w5 + w6 + w7;
    }
    for (; p < pend; ++p) {
        int s = esrc[p];
        acc += bf2f(xb[(size_t)s * 64 + ln]);
        ts += dinv[s];
    }
    ub[(size_t)wv * 64 + ln] = f2bf(acc);
    if (ln == 0) t[wv] = di + ts;
}

// ---- fused assign (MFMA, high-occupancy): block = 16 nodes, 4 waves split 512 clusters ----
#define F8ROW 520
__global__ void __launch_bounds__(256) fused_s3_kernel(
        const unsigned short* __restrict__ ub, const unsigned short* __restrict__ WaT,
        const unsigned short* __restrict__ WeT,
        const float* __restrict__ ba, const float* __restrict__ be,
        const float* __restrict__ dinv, const float* __restrict__ tsum,
        unsigned short* __restrict__ S_T, unsigned char* __restrict__ Sf8,
        unsigned short* __restrict__ Z_T, int n) {
    __shared__ float bs[512];
    __shared__ float bes[64];
    __shared__ float wmax[4][16];
    __shared__ float wsum[4][16];
    __shared__ unsigned char f8[16 * F8ROW];
    int t = threadIdx.x;
    int n0 = blockIdx.x * 16;
    {
        float b0 = (t * 2     < KK) ? ba[t * 2]     : 0.f;
        float b1 = (t * 2 + 1 < KK) ? ba[t * 2 + 1] : 0.f;
        bs[t * 2] = b0; bs[t * 2 + 1] = b1;
        if (t < 64) bes[t] = be[t];
    }
    __syncthreads();
    int wv = t >> 6, ln = t & 63;
    int nl = ln & 15;
    int g  = ln >> 4;
    int node = n0 + nl;
    int kb = wv * 128;
    float sd = (node < n) ? dinv[node] : 0.f;
    float st = (node < n) ? tsum[node] : 0.f;
    const unsigned short* brow = ub + (size_t)node * 64;
    bf16x8 bf0 = *(const bf16x8*)&brow[g * 8];
    bf16x8 bf1 = *(const bf16x8*)&brow[32 + g * 8];
    f32x4 acc[8];
#pragma unroll
    for (int mt = 0; mt < 8; ++mt) {
        const unsigned short* arow = WaT + (size_t)(kb + mt * 16 + nl) * 64;
        bf16x8 af0 = *(const bf16x8*)&arow[g * 8];
        bf16x8 af1 = *(const bf16x8*)&arow[32 + g * 8];
        f32x4 a = __builtin_amdgcn_mfma_f32_16x16x32_bf16(af0, bf0, (f32x4){0.f,0.f,0.f,0.f}, 0, 0, 0);
        acc[mt] = __builtin_amdgcn_mfma_f32_16x16x32_bf16(af1, bf1, a, 0, 0, 0);
    }
    float m = -1e30f;
#pragma unroll
    for (int mt = 0; mt < 8; ++mt) {
#pragma unroll
        for (int r = 0; r < 4; ++r) {
            int cl = kb + mt * 16 + g * 4 + r;
            float L = sd * (acc[mt][r] + st * bs[cl]);
            if (cl >= KK) L = -1e30f;
            acc[mt][r] = L;
            m = fmaxf(m, L);
        }
    }
    m = fmaxf(m, __shfl_xor(m, 16, 64));
    m = fmaxf(m, __shfl_xor(m, 32, 64));
    if (g == 0) wmax[wv][nl] = m;
    __syncthreads();
    m = fmaxf(fmaxf(wmax[0][nl], wmax[1][nl]), fmaxf(wmax[2][nl], wmax[3][nl]));
    float ssum = 0.f;
#pragma unroll
    for (int mt = 0; mt < 8; ++mt) {
#pragma unroll
        for (int r = 0; r < 4; ++r) {
            float e = expf(acc[mt][r] - m);
            acc[mt][r] = e;
            ssum += e;
        }
    }
    ssum += __shfl_xor(ssum, 16, 64);
    ssum += __shfl_xor(ssum, 32, 64);
    if (g == 0) wsum[wv][nl] = ssum;
    __syncthreads();
    float tot = (wsum[0][nl] + wsum[1][nl]) + (wsum[2][nl] + wsum[3][nl]);
    float rs = (node < n) ? (1.0f / tot) : 0.f;
    float sc = 256.f * rs;
    unsigned char* frow = &f8[nl * F8ROW];
#pragma unroll
    for (int mt = 0; mt < 8; ++mt) {
#pragma unroll
        for (int r = 0; r < 4; ++r) {
            int cl = kb + mt * 16 + g * 4 + r;
            S_T[(size_t)cl * NPAD + node] = f2bf(acc[mt][r] * rs);
        }
#ifdef HAS_FP8_CVT
        int pk = __builtin_amdgcn_cvt_pk_fp8_f32(acc[mt][0] * sc, acc[mt][1] * sc, 0, false);
        pk     = __builtin_amdgcn_cvt_pk_fp8_f32(acc[mt][2] * sc, acc[mt][3] * sc, pk, true);
#else
        int pk = (int)(f32_to_fp8_slow(acc[mt][0]*sc) | (f32_to_fp8_slow(acc[mt][1]*sc) << 8) |
                       (f32_to_fp8_slow(acc[mt][2]*sc) << 16) | (f32_to_fp8_slow(acc[mt][3]*sc) << 24));
#endif
        *(unsigned*)&frow[kb + mt * 16 + g * 4] = (unsigned)pk;
    }
    {
        const unsigned short* arow = WeT + (size_t)(wv * 16 + nl) * 64;
        bf16x8 af0 = *(const bf16x8*)&arow[g * 8];
        bf16x8 af1 = *(const bf16x8*)&arow[32 + g * 8];
        f32x4 a = __builtin_amdgcn_mfma_f32_16x16x32_bf16(af0, bf0, (f32x4){0.f,0.f,0.f,0.f}, 0, 0, 0);
        a = __builtin_amdgcn_mfma_f32_16x16x32_bf16(af1, bf1, a, 0, 0, 0);
#pragma unroll
        for (int r = 0; r < 4; ++r) {
            int ch = wv * 16 + g * 4 + r;
            float z = sd * (a[r] + st * bes[ch]);
            Z_T[(size_t)ch * NPAD + node] = f2bf(z);
        }
    }
    __syncthreads();
#pragma unroll
    for (int h = 0; h < 2; ++h) {
        int idx = t + h * 256;
        int row = idx >> 5;
        int off = (idx & 31) * 16;
        uint4 vv = *(const uint4*)&f8[row * F8ROW + off];
        int grow = n0 + row;
        if (grow < n) *(uint4*)&Sf8[(size_t)grow * KPAD + off] = vv;
    }
}

// -------- G = A^T S via in-CSR over fp8 S, TRANSPOSED bf16 out. 512 threads (8 waves). --------
#define GT_ROWS 32
__global__ void __launch_bounds__(512) g_agg_t_kernel(
        const unsigned char* __restrict__ Sf8, const int* __restrict__ offs,
        const int* __restrict__ esrc, unsigned short* __restrict__ G_T, int n) {
    __shared__ unsigned short tl[GT_ROWS * 520];
    int base = blockIdx.x * GT_ROWS;
    int wv = threadIdx.x >> 6, ln = threadIdx.x & 63;
    const uint2* S2 = (const uint2*)Sf8;
#pragma unroll
    for (int i = 0; i < GT_ROWS / 8; ++i) {
        int r = wv * (GT_ROWS / 8) + i;
        int node = base + r;
        float a[8] = {0.f,0.f,0.f,0.f,0.f,0.f,0.f,0.f};
        if (node < n) {
            int p = offs[node], pend = offs[node + 1];
            for (; p + 7 < pend; p += 8) {
                int s0 = esrc[p],     s1 = esrc[p + 1], s2 = esrc[p + 2], s3 = esrc[p + 3];
                int s4 = esrc[p + 4], s5 = esrc[p + 5], s6 = esrc[p + 6], s7 = esrc[p + 7];
                uint2 v0 = S2[(size_t)s0 * 64 + ln];
                uint2 v1 = S2[(size_t)s1 * 64 + ln];
                uint2 v2 = S2[(size_t)s2 * 64 + ln];
                uint2 v3 = S2[(size_t)s3 * 64 + ln];
                uint2 v4 = S2[(size_t)s4 * 64 + ln];
                uint2 v5 = S2[(size_t)s5 * 64 + ln];
                uint2 v6 = S2[(size_t)s6 * 64 + ln];
                uint2 v7 = S2[(size_t)s7 * 64 + ln];
                accf8(a, v0); accf8(a, v1); accf8(a, v2); accf8(a, v3);
                accf8(a, v4); accf8(a, v5); accf8(a, v6); accf8(a, v7);
            }
            for (; p < pend; ++p) {
                uint2 v = S2[(size_t)esrc[p] * 64 + ln];
                accf8(a, v);
            }
        }
        const float inv = 1.0f / 256.f;
        uint4 o;
        o.x = packbf(a[0] * inv, a[1] * inv); o.y = packbf(a[2] * inv, a[3] * inv);
        o.z = packbf(a[4] * inv, a[5] * inv); o.w = packbf(a[6] * inv, a[7] * inv);
        *(uint4*)&tl[r * 520 + ln * 8] = o;
    }
    __syncthreads();
    {
        int k = threadIdx.x;
        unsigned wb[8];
#pragma unroll
        for (int j = 0; j < 8; ++j) {
            unsigned short lo = tl[(2 * j)     * 520 + k];
            unsigned short hi = tl[(2 * j + 1) * 520 + k];
            wb[j] = ((unsigned)hi << 16) | (unsigned)lo;
        }
        unsigned wc[8];
#pragma unroll
        for (int j = 0; j < 8; ++j) {
            unsigned short lo = tl[(16 + 2 * j) * 520 + k];
            unsigned short hi = tl[(17 + 2 * j) * 520 + k];
            wc[j] = ((unsigned)hi << 16) | (unsigned)lo;
        }
        size_t ob = (size_t)k * NPAD + base;
        *(uint4*)&G_T[ob]      = make_uint4(wb[0], wb[1], wb[2], wb[3]);
        *(uint4*)&G_T[ob + 8]  = make_uint4(wb[4], wb[5], wb[6], wb[7]);
        *(uint4*)&G_T[ob + 16] = make_uint4(wc[0], wc[1], wc[2], wc[3]);
        *(uint4*)&G_T[ob + 24] = make_uint4(wc[4], wc[5], wc[6], wc[7]);
    }
}

// ---- combined MFMA TN GEMM, uniform 128x128 tiles (4 blocks/CU by LDS):
//      tiles 0..15 = next_A (G_T x S_T -> partialA), tiles 16..19 = next_X (S_T x Z_T). ----
__global__ void __launch_bounds__(256) mfma_comb_kernel(
        const unsigned short* __restrict__ S_T, const unsigned short* __restrict__ G_T,
        const unsigned short* __restrict__ Z_T,
        float* __restrict__ partialA, float* __restrict__ partialX, int nPer) {
    __shared__ unsigned short Al[128 * 72];
    __shared__ unsigned short Bl[128 * 72];
    const int tile = blockIdx.x;
    const int t = threadIdx.x;
    const int ln = t & 63, wv = t >> 6;
    const int wa = (wv & 1) * 64, wb = (wv >> 1) * 64;
    const int lm = ln & 15, lk = (ln >> 4) * 8;
    const int nbeg = blockIdx.z * nPer;
    const int nend = min(nbeg + nPer, NPAD);
    // tile -> operands/output mapping (uniform code path)
    const bool isA = (tile < 16);
    const unsigned short* Ap = isA ? G_T : S_T;
    const unsigned short* Bp = isA ? S_T : Z_T;
    const int a0 = isA ? (tile >> 2) * 128 : (tile - 16) * 128;
    const int b0 = isA ? (tile & 3) * 128 : 0;
    float* op = isA ? (partialA + (size_t)blockIdx.z * 512 * 512)
                    : (partialX + (size_t)blockIdx.z * 512 * 128);
    const int ostride = isA ? 512 : 128;
    f32x4 acc[4][4];
#pragma unroll
    for (int i = 0; i < 4; ++i)
#pragma unroll
        for (int j = 0; j < 4; ++j) acc[i][j] = (f32x4){0.f, 0.f, 0.f, 0.f};
    for (int nb = nbeg; nb < nend; nb += 64) {
        __syncthreads();
#pragma unroll
        for (int i = 0; i < 4; ++i) {
            int idx = t + i * 256;
            int r = idx >> 3, c8 = (idx & 7) * 8;
            uint4 va = *(const uint4*)&Ap[(size_t)(a0 + r) * NPAD + nb + c8];
            uint4 vb = *(const uint4*)&Bp[(size_t)(b0 + r) * NPAD + nb + c8];
            *(uint4*)&Al[r * 72 + c8] = va;
            *(uint4*)&Bl[r * 72 + c8] = vb;
        }
        __syncthreads();
#pragma unroll
        for (int ks = 0; ks < 64; ks += 32) {
            bf16x8 af[4], bfr[4];
#pragma unroll
            for (int i = 0; i < 4; ++i)
                af[i] = *(const bf16x8*)&Al[(wa + i * 16 + lm) * 72 + ks + lk];
#pragma unroll
            for (int j = 0; j < 4; ++j)
                bfr[j] = *(const bf16x8*)&Bl[(wb + j * 16 + lm) * 72 + ks + lk];
#pragma unroll
            for (int i = 0; i < 4; ++i)
#pragma unroll
                for (int j = 0; j < 4; ++j)
                    acc[i][j] = __builtin_amdgcn_mfma_f32_16x16x32_bf16(af[i], bfr[j], acc[i][j], 0, 0, 0);
        }
    }
#pragma unroll
    for (int i = 0; i < 4; ++i) {
#pragma unroll
        for (int j = 0; j < 4; ++j) {
            int bg = b0 + wb + j * 16 + lm;
#pragma unroll
            for (int r = 0; r < 4; ++r) {
                int ag = a0 + wa + i * 16 + (ln >> 4) * 4 + r;
                op[(size_t)ag * ostride + bg] = acc[i][j][r];
            }
        }
    }
}

// ---------------- combined split-K reduce (outX then outA) ----------------
__global__ void reduce2_kernel(const float* __restrict__ partialX, const float* __restrict__ partialA,
                               float* __restrict__ outX, float* __restrict__ outA, int Z) {
    int idx = blockIdx.x * blockDim.x + threadIdx.x;
    const int NX = KK * 64;          // 32000
    if (idx < NX) {
        int a = idx >> 6, b = idx & 63;
        const float* p = partialX + (size_t)a * 128 + b;
        float s = 0.f;
        for (int z = 0; z < Z; ++z) s += p[(size_t)z * 512 * 128];
        outX[idx] = s;
        return;
    }
    int j = idx - NX;
    if (j >= KK * KK) return;        // 250000
    int a = j / KK, b = j - a * KK;
    const float* p = partialA + (size_t)a * 512 + b;
    float s = 0.f;
    for (int z = 0; z < Z; ++z) s += p[(size_t)z * 512 * 512];
    outA[j] = s;
}

extern "C" void kernel_launch(void* const* d_in, const int* in_sizes, int n_in,
                              void* d_out, int out_size, void* d_ws, size_t ws_size,
                              hipStream_t stream) {
    const float* x        = (const float*)d_in[0];
    const int*   ei       = (const int*)d_in[1];
    const float* W_embed  = (const float*)d_in[2];
    const float* b_embed  = (const float*)d_in[3];
    const float* W_assign = (const float*)d_in[4];
    const float* b_assign = (const float*)d_in[5];

    const int N = in_sizes[0] / DD;     // 50000
    const int E = in_sizes[1] / 2;      // 800000
    const int C = in_sizes[3];          // 64
    const int K = in_sizes[5];          // 500

    const int* rowv = ei;
    const int* colv = ei + E;

    char* p = (char*)d_ws;
    auto alloc = [&](size_t bytes) -> void* {
        void* r = (void*)p;
        p += (bytes + 255) & ~(size_t)255;
        return r;
    };
    int*   cnt      = (int*)alloc((size_t)2 * NS * 4);
    int*   cnt_col  = cnt;
    int*   cnt_row  = cnt + NS;
    int*   offs_col = (int*)alloc((size_t)(N + 1) * 4);
    int*   cur_col  = (int*)alloc((size_t)N * 4);
    int*   bsum     = (int*)alloc(64 * 4);
    int*   bbase    = (int*)alloc(64 * 4);
    float* dinv     = (float*)alloc((size_t)N * 4);
    float* tsum     = (float*)alloc((size_t)N * 4);
    int*   esrc     = (int*)alloc((size_t)E * 4);
    float* u        = (float*)alloc((size_t)N * DD * 4);                   // 12.8 MB (partialX)
    unsigned short* xb   = (unsigned short*)alloc((size_t)N * DD * 2);
    unsigned short* ubuf = (unsigned short*)alloc((size_t)NPAD * DD * 2);
    unsigned short* WaT  = (unsigned short*)alloc((size_t)KPAD * DD * 2);
    unsigned short* WeT  = (unsigned short*)alloc((size_t)DD * DD * 2);
    unsigned char*  Sf8  = (unsigned char*)alloc((size_t)N * KPAD);
    unsigned short* S_T  = (unsigned short*)alloc((size_t)KPAD * NPAD * 2);
    unsigned short* G_T  = (unsigned short*)alloc((size_t)KPAD * NPAD * 2);
    unsigned short* Z_T  = (unsigned short*)alloc((size_t)128 * NPAD * 2);

    // split-K (nPer=1088, Z=46: 1088*46 == NPAD)
    const int nPer = 1088, ZSK = 46;
    float* partialA = (float*)alloc((size_t)ZSK * 512 * 512 * 4);          // 48.2 MB
    float* partialX = (float*)u;    // 46*512*128*4 = 12.06 MB <= 12.8 MB

    float* outX = (float*)d_out;            // [500][64]
    float* outA = outX + (size_t)K * C;     // [500][500]

    const int NB = (N + 1023) / 1024;

    (void)hipMemsetAsync(cnt, 0, (size_t)2 * NS * 4, stream);

    hist_kernel<<<(E + 255) / 256, 256, 0, stream>>>(rowv, colv, cnt_row, cnt_col, E);
    scanA_kernel<<<NB, 256, 0, stream>>>(cnt_col, bsum);
    scanB_kernel<<<1, 64, 0, stream>>>(bsum, bbase, &offs_col[N], NB);
    scanC_kernel<<<NB, 256, 0, stream>>>(cnt_col, cnt_row, bbase, offs_col, cur_col, dinv, N);
    place_kernel<<<(E + 255) / 256, 256, 0, stream>>>(rowv, colv, cur_col, esrc, E);

    // fused prep: xb + WaT + WeT
    {
        int total = N * 16 + (KPAD + DD) * 64;
        prep_kernel<<<(total + 255) / 256, 256, 0, stream>>>(x, dinv, xb, W_assign, W_embed,
                                                             WaT, WeT, N * 16);
    }

    agg_kernel<<<NPAD / 4, 256, 0, stream>>>(xb, dinv, offs_col, esrc, tsum, ubuf, N);

    fused_s3_kernel<<<NPAD / 16, 256, 0, stream>>>(ubuf, WaT, WeT, b_assign, b_embed,
                                                   dinv, tsum, S_T, Sf8, Z_T, N);

    g_agg_t_kernel<<<NPAD / GT_ROWS, 512, 0, stream>>>(Sf8, offs_col, esrc, G_T, N);

    // combined GEMM: next_A (tiles 0..15) + next_X (tiles 16..19), uniform 128x128
    {
        dim3 g(20, 1, ZSK);
        mfma_comb_kernel<<<g, 256, 0, stream>>>(S_T, G_T, Z_T, partialA, partialX, nPer);
    }
    // combined reduce
    {
        int total = K * C + K * K;   // 282000
        reduce2_kernel<<<(total + 255) / 256, 256, 0, stream>>>(partialX, partialA, outX, outA, ZSK);
    }
}